// Round 14
// baseline (453.783 us; speedup 1.0000x reference)
//
#include <hip/hip_runtime.h>

#define HID 128

typedef __attribute__((ext_vector_type(8))) short short8;
typedef __attribute__((ext_vector_type(4))) float f32x4;

__device__ __forceinline__ float bf2f(unsigned short u) {
    unsigned int x = ((unsigned int)u) << 16;
    return __builtin_bit_cast(float, x);
}
__device__ __forceinline__ unsigned short f2bf(float f) {
    unsigned int u = __builtin_bit_cast(unsigned int, f);
    u += 0x7fffu + ((u >> 16) & 1u);
    return (unsigned short)(u >> 16);
}

// fp32 [K,N] (optionally two stacked sources) -> fragment layout hi/lo:
// elem (k,n) at ((k/32)*N + n)*32 + k%32
__device__ __forceinline__ void prep_one(const float* __restrict__ s1, int k1,
    const float* __restrict__ s2, int N, int i,
    unsigned short* __restrict__ whi, unsigned short* __restrict__ wlo)
{
    int k = i / N, nn = i - k * N;
    float v = (k < k1) ? s1[(size_t)k * N + nn]
                       : (s2 ? s2[(size_t)(k - k1) * N + nn] : 0.f);
    unsigned short h = f2bf(v);
    unsigned short l = f2bf(v - bf2f(h));
    size_t o = ((size_t)(k >> 5) * N + nn) * 32 + (k & 31);
    whi[o] = h; wlo[o] = l;
}

// ---------------- merged prep: all 4 weight preps + zero-row/gCur init, one dispatch ----------------
// blocks [0,48): w_in (96x128)   [48,176): w1 (256x128)   [176,304): w2 (256x128)
// [304,336): wh1 (128x64)        336: zero rows z1,z2 (256 shorts each) + gCur (512 ints)
__global__ __launch_bounds__(256) void k_prep(
    const float* __restrict__ w_in, const float* __restrict__ w1l,
    const float* __restrict__ w1r, const float* __restrict__ w2l,
    const float* __restrict__ w2r, const float* __restrict__ wh1,
    unsigned short* __restrict__ w0h, unsigned short* __restrict__ w0l,
    unsigned short* __restrict__ w1h, unsigned short* __restrict__ w1lo,
    unsigned short* __restrict__ w2h, unsigned short* __restrict__ w2lo,
    unsigned short* __restrict__ whh, unsigned short* __restrict__ whl,
    unsigned short* __restrict__ z1, unsigned short* __restrict__ z2,
    int* __restrict__ gCur)
{
    int b = blockIdx.x, t = threadIdx.x;
    if (b < 48) {
        prep_one(w_in, 71, nullptr, 128, b * 256 + t, w0h, w0l);
    } else if (b < 176) {
        prep_one(w1l, 128, w1r, 128, (b - 48) * 256 + t, w1h, w1lo);
    } else if (b < 304) {
        prep_one(w2l, 128, w2r, 128, (b - 176) * 256 + t, w2h, w2lo);
    } else if (b < 336) {
        prep_one(wh1, 128, nullptr, 64, (b - 304) * 256 + t, whh, whl);
    } else {
        z1[t] = 0; z2[t] = 0;
        gCur[t] = 0; gCur[t + 256] = 0;
    }
}

// ---------------- input feature prestack: [xnum | emb0..3 | pad] -> bf16,
// A0 row-major [n][96].  6 chunks of 16 cols per row. ----------------
__global__ __launch_bounds__(256) void k_stack0(
    const float* __restrict__ xnum, const int* __restrict__ xcat,
    const float* __restrict__ e0, const float* __restrict__ e1,
    const float* __restrict__ e2, const float* __restrict__ e3,
    unsigned short* __restrict__ A0, int n)
{
    int g = blockIdx.x * 256 + threadIdx.x;
    int r = g / 6, c = g - r * 6;              // 6 chunks of 16 cols (96 features)
    if (r >= n) return;
    int4 cc = ((const int4*)xcat)[r];
    float v[16];
    int base = c * 16;
    #pragma unroll
    for (int j = 0; j < 16; ++j) {
        int col = base + j;
        float val;
        if      (col < 32) val = xnum[(size_t)r * 32 + col];
        else if (col < 42) val = e0[(size_t)cc.x * 10 + (col - 32)];
        else if (col < 48) val = e1[(size_t)cc.y * 6  + (col - 42)];
        else if (col < 53) val = e2[(size_t)cc.z * 5  + (col - 48)];
        else if (col < 71) val = e3[(size_t)cc.w * 18 + (col - 53)];
        else               val = 0.f;
        v[j] = val;
    }
    unsigned int ph[8];
    #pragma unroll
    for (int j = 0; j < 8; ++j)
        ph[j] = (unsigned int)f2bf(v[2*j]) | ((unsigned int)f2bf(v[2*j+1]) << 16);
    unsigned int* dh = (unsigned int*)(A0 + (size_t)r * 96 + base);
    uint4 a; a.x = ph[0]; a.y = ph[1]; a.z = ph[2]; a.w = ph[3];
    uint4 b; b.x = ph[4]; b.y = ph[5]; b.z = ph[6]; b.w = ph[7];
    ((uint4*)dh)[0] = a; ((uint4*)dh)[1] = b;
}

// ---------------- CSR build via bucketed counting sort (LDS atomics) ----------------
__global__ __launch_bounds__(256) void k_part(const int* __restrict__ esrc,
    const int* __restrict__ edst, int* __restrict__ gCur, int2* __restrict__ ebuf,
    int ecount, int chunk, int cap)
{
    __shared__ int hist[512];
    __shared__ int base[512];
    int t = threadIdx.x;
    hist[t] = 0; hist[t + 256] = 0;
    __syncthreads();
    int start = blockIdx.x * chunk;
    int end = start + chunk < ecount ? start + chunk : ecount;
    for (int i = start + t; i < end; i += 256)
        atomicAdd(&hist[edst[i] >> 8], 1);          // LDS
    __syncthreads();
    for (int bk = t; bk < 512; bk += 256) {
        int h = hist[bk];
        base[bk] = h ? atomicAdd(&gCur[bk], h) : 0; // global, 1 per (block,bucket)
        hist[bk] = 0;
    }
    __syncthreads();
    for (int i = start + t; i < end; i += 256) {
        int d = edst[i];
        int b = d >> 8;
        int slot = atomicAdd(&hist[b], 1);          // LDS
        int pos = base[b] + slot;
        if (pos < cap)
            ebuf[(size_t)b * cap + pos] = make_int2(esrc[i], d);
    }
}

__global__ __launch_bounds__(512) void k_scanb(const int* __restrict__ gCur,
    int* __restrict__ bBase, int* __restrict__ row_ptr, int nbuck, int n, int ecount)
{
    __shared__ int sm[512];
    int t = threadIdx.x;
    int c = (t < nbuck) ? gCur[t] : 0;
    sm[t] = c;
    __syncthreads();
    for (int d = 1; d < 512; d <<= 1) {
        int v = (t >= d) ? sm[t - d] : 0;
        __syncthreads();
        sm[t] += v;
        __syncthreads();
    }
    if (t < nbuck) bBase[t] = sm[t] - c;
    if (t == 0) row_ptr[n] = ecount;
}

__global__ __launch_bounds__(256) void k_bcsr(const int2* __restrict__ ebuf,
    const int* __restrict__ gCur, const int* __restrict__ bBase,
    int* __restrict__ row_ptr, int* __restrict__ col, int cap, int n)
{
    __shared__ int h[256];
    __shared__ int sm[256];
    int b = blockIdx.x, t = threadIdx.x;
    int cnt = gCur[b];
    int nb0 = b << 8;
    const int2* eb = ebuf + (size_t)b * cap;
    h[t] = 0;
    __syncthreads();
    for (int i = t; i < cnt; i += 256)
        atomicAdd(&h[eb[i].y & 255], 1);            // LDS histogram
    __syncthreads();
    int hv = h[t];
    sm[t] = hv;
    __syncthreads();
    for (int d = 1; d < 256; d <<= 1) {
        int v = (t >= d) ? sm[t - d] : 0;
        __syncthreads();
        sm[t] += v;
        __syncthreads();
    }
    int excl = sm[t] - hv;
    int gb = bBase[b];
    int g = nb0 + t;
    if (g < n) row_ptr[g] = gb + excl;
    __syncthreads();
    h[t] = excl;                                    // reuse as cursor
    __syncthreads();
    for (int i = t; i < cnt; i += 256) {
        int2 e = eb[i];
        int slot = atomicAdd(&h[e.y & 255], 1);     // LDS
        col[gb + slot] = e.x;
    }
}

// ---------------- mean aggregation (bf16): quarter-wave per edge ----------------
// 16 lanes x uint4 cover a 256 B row; ALWAYS 4 gathers in flight — out-of-range
// edges redirect to zero row `zr` (branchless, address-clamped col loads).
__global__ __launch_bounds__(256) void k_agg(
    const unsigned short* __restrict__ xh, unsigned short* __restrict__ mh, int SK,
    const int* __restrict__ row_ptr, const int* __restrict__ col, int n,
    int zr, int emax)
{
    int lane = threadIdx.x & 63;
    int qw  = lane >> 4;
    int l16 = lane & 15;
    int node = blockIdx.x * 4 + (threadIdx.x >> 6);
    if (node >= n) return;
    node = __builtin_amdgcn_readfirstlane(node);
    int s = row_ptr[node], e = row_ptr[node + 1];
    int deg = e - s;
    float a0 = 0.f, a1 = 0.f, a2 = 0.f, a3 = 0.f;
    float a4 = 0.f, a5 = 0.f, a6 = 0.f, a7 = 0.f;
    size_t cOff = (size_t)l16 * 8;        // 8 bf16 cols per lane

    auto accum = [&](uint4 r) {
        a0 += __builtin_bit_cast(float, r.x << 16);
        a1 += __builtin_bit_cast(float, r.x & 0xffff0000u);
        a2 += __builtin_bit_cast(float, r.y << 16);
        a3 += __builtin_bit_cast(float, r.y & 0xffff0000u);
        a4 += __builtin_bit_cast(float, r.z << 16);
        a5 += __builtin_bit_cast(float, r.z & 0xffff0000u);
        a6 += __builtin_bit_cast(float, r.w << 16);
        a7 += __builtin_bit_cast(float, r.w & 0xffff0000u);
    };

    int em1 = emax - 1;
    for (int p = s + qw; p < e; p += 16) {
        int p1 = p + 4, p2 = p + 8, p3 = p + 12;
        int q1 = p1 < em1 ? p1 : em1;
        int q2 = p2 < em1 ? p2 : em1;
        int q3 = p3 < em1 ? p3 : em1;
        int t0 = col[p];
        int t1 = col[q1];
        int t2 = col[q2];
        int t3 = col[q3];
        int c0 = t0;
        int c1 = (p1 < e) ? t1 : zr;
        int c2 = (p2 < e) ? t2 : zr;
        int c3 = (p3 < e) ? t3 : zr;
        uint4 r0 = *(const uint4*)(xh + (size_t)c0 * SK + cOff);
        uint4 r1 = *(const uint4*)(xh + (size_t)c1 * SK + cOff);
        uint4 r2 = *(const uint4*)(xh + (size_t)c2 * SK + cOff);
        uint4 r3 = *(const uint4*)(xh + (size_t)c3 * SK + cOff);
        accum(r0); accum(r1); accum(r2); accum(r3);
    }

    a0 += __shfl_xor(a0, 16); a0 += __shfl_xor(a0, 32);
    a1 += __shfl_xor(a1, 16); a1 += __shfl_xor(a1, 32);
    a2 += __shfl_xor(a2, 16); a2 += __shfl_xor(a2, 32);
    a3 += __shfl_xor(a3, 16); a3 += __shfl_xor(a3, 32);
    a4 += __shfl_xor(a4, 16); a4 += __shfl_xor(a4, 32);
    a5 += __shfl_xor(a5, 16); a5 += __shfl_xor(a5, 32);
    a6 += __shfl_xor(a6, 16); a6 += __shfl_xor(a6, 32);
    a7 += __shfl_xor(a7, 16); a7 += __shfl_xor(a7, 32);

    if (qw == 0) {
        float inv = 1.f / (float)(deg > 1 ? deg : 1);
        uint4 o;
        o.x = (unsigned int)f2bf(a0 * inv) | ((unsigned int)f2bf(a1 * inv) << 16);
        o.y = (unsigned int)f2bf(a2 * inv) | ((unsigned int)f2bf(a3 * inv) << 16);
        o.z = (unsigned int)f2bf(a4 * inv) | ((unsigned int)f2bf(a5 * inv) << 16);
        o.w = (unsigned int)f2bf(a6 * inv) | ((unsigned int)f2bf(a7 * inv) << 16);
        *(uint4*)(mh + (size_t)node * SK + cOff) = o;
    }
}

// ---------------- split-weight bf16-activation MFMA GEMM, M-tile=32, block=256 ----------------
// M-tile halved 64->32 (r14): grid doubles to ~3125 -> ~12 blocks/CU available,
// LDS 16.9 KB + 4 waves/block allow 8 blocks/CU resident (~100% static occupancy)
// vs r13's 6.1-block grid at 25% measured — more TLP to hide the L2/L3-latency-bound
// K-loop chains.  W re-read by 2x blocks is L2-hot (idle L2 BW).
// A row-major bf16 [m][SK], SK = KT8*32.  Weights split hi/lo.
// K-loop (#pragma unroll 1): per k-tile load ah,bh,bl once; groups Ah·Wh, Ah·Wl.
// Epilogue single phase (32 rows = 256 threads / 8 per row), 8 threads/row.
// EPI 0: out = relu(C+bias) -> bf16 store.  EPI 1: LN+relu, out = res + 0.5*r -> bf16 store.
// EPI 2: head: s = relu(C+bias)·wh2 + bh2 -> outp.
template<int NC, int KT8, int EPI>
__global__ __launch_bounds__(256) void k_gemm(
    const unsigned short* __restrict__ A, int SK,
    const unsigned short* __restrict__ Whi, const unsigned short* __restrict__ Wlo,
    const float* __restrict__ bias,
    const float* __restrict__ g, const float* __restrict__ be,
    const unsigned short* __restrict__ Src, int SSK,
    unsigned short* __restrict__ Dst, int DSK,
    const float* __restrict__ wh2, const float* __restrict__ bh2, float* __restrict__ outp,
    int n)
{
    constexpr int NT = NC / 64;       // n-16-tiles per wave
    __shared__ float Cb[32][NC + 4];
    int t = threadIdx.x;
    int lane = t & 63, w = t >> 6;
    int l15 = lane & 15, kg = lane >> 4;
    int m0 = blockIdx.x * 32;

    size_t aoff[2];
    #pragma unroll
    for (int mt = 0; mt < 2; ++mt) {
        int r = m0 + mt * 16 + l15;
        r = r < n ? r : n - 1;
        aoff[mt] = (size_t)r * SK + kg * 8;
    }
    size_t nb[NT];
    #pragma unroll
    for (int nt = 0; nt < NT; ++nt)
        nb[nt] = (size_t)(w * (NC / 4) + nt * 16 + l15) * 32 + kg * 8;

    f32x4 acc[2][NT];
    #pragma unroll
    for (int mt = 0; mt < 2; ++mt)
        #pragma unroll
        for (int nt = 0; nt < NT; ++nt)
            acc[mt][nt] = (f32x4)(0.f);

    #pragma unroll 1
    for (int s = 0; s < KT8; ++s) {
        int koff = s * 32;
        short8 ah[2];
        #pragma unroll
        for (int mt = 0; mt < 2; ++mt)
            ah[mt] = *(const short8*)(A + aoff[mt] + koff);
        short8 bh[NT], bl[NT];
        #pragma unroll
        for (int nt = 0; nt < NT; ++nt) {
            bh[nt] = *(const short8*)(Whi + (size_t)s * NC * 32 + nb[nt]);
            bl[nt] = *(const short8*)(Wlo + (size_t)s * NC * 32 + nb[nt]);
        }
        #pragma unroll
        for (int mt = 0; mt < 2; ++mt)
            #pragma unroll
            for (int nt = 0; nt < NT; ++nt)
                acc[mt][nt] = __builtin_amdgcn_mfma_f32_16x16x32_bf16(ah[mt], bh[nt], acc[mt][nt], 0, 0, 0);
        #pragma unroll
        for (int mt = 0; mt < 2; ++mt)
            #pragma unroll
            for (int nt = 0; nt < NT; ++nt)
                acc[mt][nt] = __builtin_amdgcn_mfma_f32_16x16x32_bf16(ah[mt], bl[nt], acc[mt][nt], 0, 0, 0);
    }

    // Epilogue: single phase, 32 rows.  C/D layout: col = lane&15, row = quad*4 + reg.
    #pragma unroll
    for (int mt = 0; mt < 2; ++mt)
        #pragma unroll
        for (int nt = 0; nt < NT; ++nt)
            #pragma unroll
            for (int r = 0; r < 4; ++r)
                Cb[mt * 16 + kg * 4 + r][w * (NC / 4) + nt * 16 + l15] = acc[mt][nt][r];
    __syncthreads();

    constexpr int CW = NC / 8;        // cols per epilogue thread (8 threads/row)
    int er = t >> 3, q = t & 7;
    int cb = q * CW;
    int gr = m0 + er;

    if (EPI == 0) {
        if (gr < n) {
            #pragma unroll
            for (int i = 0; i < CW / 4; ++i) {
                int c = cb + 4 * i;
                float4 v  = *(const float4*)&Cb[er][c];
                float4 bi = *(const float4*)&bias[c];
                ushort4 hv = make_ushort4(f2bf(fmaxf(v.x + bi.x, 0.f)),
                                          f2bf(fmaxf(v.y + bi.y, 0.f)),
                                          f2bf(fmaxf(v.z + bi.z, 0.f)),
                                          f2bf(fmaxf(v.w + bi.w, 0.f)));
                *(ushort4*)(Dst + (size_t)gr * DSK + c) = hv;
            }
        }
    } else if (EPI == 1) {
        float s = 0.f, ss = 0.f;
        #pragma unroll
        for (int i = 0; i < CW / 4; ++i) {
            int c = cb + 4 * i;
            float4 v  = *(const float4*)&Cb[er][c];
            float4 bi = *(const float4*)&bias[c];
            float a0 = v.x + bi.x, a1 = v.y + bi.y, a2 = v.z + bi.z, a3 = v.w + bi.w;
            s  += a0 + a1 + a2 + a3;
            ss += a0 * a0 + a1 * a1 + a2 * a2 + a3 * a3;
        }
        s  += __shfl_xor(s, 1);  s  += __shfl_xor(s, 2);  s  += __shfl_xor(s, 4);
        ss += __shfl_xor(ss, 1); ss += __shfl_xor(ss, 2); ss += __shfl_xor(ss, 4);
        float mu  = s * (1.f / NC);
        float var = ss * (1.f / NC) - mu * mu;
        float rs  = rsqrtf(var + 1e-5f);
        if (gr < n) {
            #pragma unroll
            for (int i = 0; i < CW / 4; ++i) {
                int c = cb + 4 * i;
                float4 v  = *(const float4*)&Cb[er][c];
                float4 bi = *(const float4*)&bias[c];
                float4 gg = *(const float4*)&g[c];
                float4 bb = *(const float4*)&be[c];
                float r0 = fmaxf((v.x + bi.x - mu) * rs * gg.x + bb.x, 0.f);
                float r1 = fmaxf((v.y + bi.y - mu) * rs * gg.y + bb.y, 0.f);
                float r2 = fmaxf((v.z + bi.z - mu) * rs * gg.z + bb.z, 0.f);
                float r3 = fmaxf((v.w + bi.w - mu) * rs * gg.w + bb.w, 0.f);
                ushort4 rh = *(const ushort4*)(Src + (size_t)gr * SSK + c);
                ushort4 hv = make_ushort4(f2bf(bf2f(rh.x) + 0.5f * r0),
                                          f2bf(bf2f(rh.y) + 0.5f * r1),
                                          f2bf(bf2f(rh.z) + 0.5f * r2),
                                          f2bf(bf2f(rh.w) + 0.5f * r3));
                *(ushort4*)(Dst + (size_t)gr * DSK + c) = hv;
            }
        }
    } else {
        float s = 0.f;
        #pragma unroll
        for (int i = 0; i < CW / 4; ++i) {
            int c = cb + 4 * i;
            float4 v  = *(const float4*)&Cb[er][c];
            float4 bi = *(const float4*)&bias[c];
            float4 w2 = *(const float4*)&wh2[c];
            s += fmaxf(v.x + bi.x, 0.f) * w2.x + fmaxf(v.y + bi.y, 0.f) * w2.y
               + fmaxf(v.z + bi.z, 0.f) * w2.z + fmaxf(v.w + bi.w, 0.f) * w2.w;
        }
        s += __shfl_xor(s, 1); s += __shfl_xor(s, 2); s += __shfl_xor(s, 4);
        if (q == 0 && gr < n) outp[gr] = s + bh2[0];
    }
}

// ---------------- launcher ----------------
extern "C" void kernel_launch(void* const* d_in, const int* in_sizes, int n_in,
                              void* d_out, int out_size, void* d_ws, size_t ws_size,
                              hipStream_t stream)
{
    const float* xnum = (const float*)d_in[0];
    const int*   xcat = (const int*)d_in[1];
    const int*   eidx = (const int*)d_in[2];
    const float* e0   = (const float*)d_in[3];
    const float* e1   = (const float*)d_in[4];
    const float* e2   = (const float*)d_in[5];
    const float* e3   = (const float*)d_in[6];
    const float* w_in = (const float*)d_in[7];
    const float* b_in = (const float*)d_in[8];
    const float* w1l  = (const float*)d_in[9];
    const float* b1l  = (const float*)d_in[10];
    const float* w1r  = (const float*)d_in[11];
    const float* w2l  = (const float*)d_in[12];
    const float* b2l  = (const float*)d_in[13];
    const float* w2r  = (const float*)d_in[14];
    const float* g1   = (const float*)d_in[15];
    const float* be1  = (const float*)d_in[16];
    const float* g2   = (const float*)d_in[17];
    const float* be2  = (const float*)d_in[18];
    const float* wh1  = (const float*)d_in[19];
    const float* bh1  = (const float*)d_in[20];
    const float* wh2  = (const float*)d_in[21];
    const float* bh2  = (const float*)d_in[22];

    int n = in_sizes[0] / 32;
    int ecount = in_sizes[2] / 2;
    const int* esrc = eidx;
    const int* edst = eidx + ecount;

    char* ws = (char*)d_ws;
    size_t off = 0;
    auto alloc = [&](size_t bytes) -> void* {
        void* p = ws + off;
        off += (bytes + 255) & ~(size_t)255;
        return p;
    };
    // A1: (n+1) x 256 bf16 = [mean1(128) | x0(128)]; row n = zero row for agg redirect.
    // A3 (n x 128, x2) aliases it.  A2: (n+1) x 256 = [mean2 | x1]; A0 (n x 96) aliases A2.
    unsigned short* A1 = (unsigned short*)alloc((size_t)(n + 1) * 256 * 2);
    unsigned short* A3 = A1;
    unsigned short* A2 = (unsigned short*)alloc((size_t)(n + 1) * 256 * 2);
    unsigned short* A0 = A2;
    // Weight fragment buffers (hi/lo split)
    unsigned short* w0h = (unsigned short*)alloc((size_t)96 * 128 * 2);
    unsigned short* w0l = (unsigned short*)alloc((size_t)96 * 128 * 2);
    unsigned short* w1h = (unsigned short*)alloc((size_t)256 * 128 * 2);
    unsigned short* w1lo= (unsigned short*)alloc((size_t)256 * 128 * 2);
    unsigned short* w2h = (unsigned short*)alloc((size_t)256 * 128 * 2);
    unsigned short* w2lo= (unsigned short*)alloc((size_t)256 * 128 * 2);
    unsigned short* whh = (unsigned short*)alloc((size_t)128 * 64 * 2);
    unsigned short* whl = (unsigned short*)alloc((size_t)128 * 64 * 2);
    // CSR via bucketed counting sort
    int nbuck = (n + 255) >> 8;
    int cap = ecount / nbuck + ecount / (2 * nbuck) + 256;   // mean + 50% + slack
    int* gCur    = (int*)alloc(512 * 4);
    int* bBase   = (int*)alloc(512 * 4);
    int* row_ptr = (int*)alloc((size_t)(n + 1) * 4);
    int* col     = (int*)alloc((size_t)ecount * 4);
    int2* ebuf   = (int2*)alloc((size_t)nbuck * cap * 8);
    (void)ws_size; (void)n_in; (void)out_size;

    int gemmBlocks = (n + 31) / 32;
    int aggBlocks = (n + 3) / 4;

    // merged weight prep + zero-row + gCur init (one dispatch, no memsets)
    k_prep<<<337, 256, 0, stream>>>(
        w_in, w1l, w1r, w2l, w2r, wh1,
        w0h, w0l, w1h, w1lo, w2h, w2lo, whh, whl,
        A1 + (size_t)n * 256, A2 + (size_t)n * 256, gCur);

    // input features -> A0 (bf16, 96 cols)
    k_stack0<<<((size_t)n * 6 + 255) / 256, 256, 0, stream>>>(xnum, xcat, e0, e1, e2, e3, A0, n);

    // CSR build: partition -> bucket scan -> per-bucket CSR
    int nblkP = 512;
    int chunk = (ecount + nblkP - 1) / nblkP;
    k_part<<<nblkP, 256, 0, stream>>>(esrc, edst, gCur, ebuf, ecount, chunk, cap);
    k_scanb<<<1, 512, 0, stream>>>(gCur, bBase, row_ptr, nbuck, n, ecount);
    k_bcsr<<<nbuck, 256, 0, stream>>>(ebuf, gCur, bBase, row_ptr, col, cap, n);

    // input MLP: A0[96] @ W0 -> x0 bf16 -> A1 x-slot (cols 128..255)
    k_gemm<128, 3, 0><<<gemmBlocks, 256, 0, stream>>>(
        A0, 96, w0h, w0l, b_in,
        nullptr, nullptr, nullptr, 0,
        A1 + 128, 256,
        nullptr, nullptr, nullptr, n);

    // conv1: mean of x0 -> A1 cols 0..127; GEMM A1[256] @ [w1l;w1r] -> x1 -> A2 x-slot
    k_agg<<<aggBlocks, 256, 0, stream>>>(A1 + 128, A1, 256, row_ptr, col, n, n, ecount);
    k_gemm<128, 8, 1><<<gemmBlocks, 256, 0, stream>>>(
        A1, 256, w1h, w1lo, b1l,
        g1, be1, A1 + 128, 256,
        A2 + 128, 256,
        nullptr, nullptr, nullptr, n);

    // conv2: mean of x1 -> A2 cols 0..127; GEMM A2[256] -> x2 -> A3 (128 cols/row)
    k_agg<<<aggBlocks, 256, 0, stream>>>(A2 + 128, A2, 256, row_ptr, col, n, n, ecount);
    k_gemm<128, 8, 1><<<gemmBlocks, 256, 0, stream>>>(
        A2, 256, w2h, w2lo, b2l,
        g2, be2, A2 + 128, 256,
        A3, 128,
        nullptr, nullptr, nullptr, n);

    // head: A3[128] @ wh1 -> relu -> ·wh2 + bh2 -> out
    k_gemm<64, 4, 2><<<gemmBlocks, 256, 0, stream>>>(
        A3, 128, whh, whl, bh1,
        nullptr, nullptr, nullptr, 0,
        nullptr, 0,
        wh2, bh2, (float*)d_out, n);
}

// Round 15
// 442.692 us; speedup vs baseline: 1.0251x; 1.0251x over previous
//
#include <hip/hip_runtime.h>

#define HID 128

typedef __attribute__((ext_vector_type(8))) short short8;
typedef __attribute__((ext_vector_type(4))) float f32x4;

__device__ __forceinline__ float bf2f(unsigned short u) {
    unsigned int x = ((unsigned int)u) << 16;
    return __builtin_bit_cast(float, x);
}
__device__ __forceinline__ unsigned short f2bf(float f) {
    unsigned int u = __builtin_bit_cast(unsigned int, f);
    u += 0x7fffu + ((u >> 16) & 1u);
    return (unsigned short)(u >> 16);
}

// fp32 [K,N] (optionally two stacked sources) -> fragment layout hi/lo:
// elem (k,n) at ((k/32)*N + n)*32 + k%32
__device__ __forceinline__ void prep_one(const float* __restrict__ s1, int k1,
    const float* __restrict__ s2, int N, int i,
    unsigned short* __restrict__ whi, unsigned short* __restrict__ wlo)
{
    int k = i / N, nn = i - k * N;
    float v = (k < k1) ? s1[(size_t)k * N + nn]
                       : (s2 ? s2[(size_t)(k - k1) * N + nn] : 0.f);
    unsigned short h = f2bf(v);
    unsigned short l = f2bf(v - bf2f(h));
    size_t o = ((size_t)(k >> 5) * N + nn) * 32 + (k & 31);
    whi[o] = h; wlo[o] = l;
}

// ---------------- merged prep: all 4 weight preps + zero-row/gCur init, one dispatch ----------------
__global__ __launch_bounds__(256) void k_prep(
    const float* __restrict__ w_in, const float* __restrict__ w1l,
    const float* __restrict__ w1r, const float* __restrict__ w2l,
    const float* __restrict__ w2r, const float* __restrict__ wh1,
    unsigned short* __restrict__ w0h, unsigned short* __restrict__ w0l,
    unsigned short* __restrict__ w1h, unsigned short* __restrict__ w1lo,
    unsigned short* __restrict__ w2h, unsigned short* __restrict__ w2lo,
    unsigned short* __restrict__ whh, unsigned short* __restrict__ whl,
    unsigned short* __restrict__ z1, unsigned short* __restrict__ z2,
    int* __restrict__ gCur)
{
    int b = blockIdx.x, t = threadIdx.x;
    if (b < 48) {
        prep_one(w_in, 71, nullptr, 128, b * 256 + t, w0h, w0l);
    } else if (b < 176) {
        prep_one(w1l, 128, w1r, 128, (b - 48) * 256 + t, w1h, w1lo);
    } else if (b < 304) {
        prep_one(w2l, 128, w2r, 128, (b - 176) * 256 + t, w2h, w2lo);
    } else if (b < 336) {
        prep_one(wh1, 128, nullptr, 64, (b - 304) * 256 + t, whh, whl);
    } else {
        z1[t] = 0; z2[t] = 0;
        gCur[t] = 0; gCur[t + 256] = 0;
    }
}

// ---------------- input feature prestack: [xnum | emb0..3 | pad] -> bf16,
// A0 row-major [n][96].  6 chunks of 16 cols per row. ----------------
__global__ __launch_bounds__(256) void k_stack0(
    const float* __restrict__ xnum, const int* __restrict__ xcat,
    const float* __restrict__ e0, const float* __restrict__ e1,
    const float* __restrict__ e2, const float* __restrict__ e3,
    unsigned short* __restrict__ A0, int n)
{
    int g = blockIdx.x * 256 + threadIdx.x;
    int r = g / 6, c = g - r * 6;              // 6 chunks of 16 cols (96 features)
    if (r >= n) return;
    int4 cc = ((const int4*)xcat)[r];
    float v[16];
    int base = c * 16;
    #pragma unroll
    for (int j = 0; j < 16; ++j) {
        int col = base + j;
        float val;
        if      (col < 32) val = xnum[(size_t)r * 32 + col];
        else if (col < 42) val = e0[(size_t)cc.x * 10 + (col - 32)];
        else if (col < 48) val = e1[(size_t)cc.y * 6  + (col - 42)];
        else if (col < 53) val = e2[(size_t)cc.z * 5  + (col - 48)];
        else if (col < 71) val = e3[(size_t)cc.w * 18 + (col - 53)];
        else               val = 0.f;
        v[j] = val;
    }
    unsigned int ph[8];
    #pragma unroll
    for (int j = 0; j < 8; ++j)
        ph[j] = (unsigned int)f2bf(v[2*j]) | ((unsigned int)f2bf(v[2*j+1]) << 16);
    unsigned int* dh = (unsigned int*)(A0 + (size_t)r * 96 + base);
    uint4 a; a.x = ph[0]; a.y = ph[1]; a.z = ph[2]; a.w = ph[3];
    uint4 b; b.x = ph[4]; b.y = ph[5]; b.z = ph[6]; b.w = ph[7];
    ((uint4*)dh)[0] = a; ((uint4*)dh)[1] = b;
}

// ---------------- CSR build via bucketed counting sort (LDS atomics) ----------------
__global__ __launch_bounds__(256) void k_part(const int* __restrict__ esrc,
    const int* __restrict__ edst, int* __restrict__ gCur, int2* __restrict__ ebuf,
    int ecount, int chunk, int cap)
{
    __shared__ int hist[512];
    __shared__ int base[512];
    int t = threadIdx.x;
    hist[t] = 0; hist[t + 256] = 0;
    __syncthreads();
    int start = blockIdx.x * chunk;
    int end = start + chunk < ecount ? start + chunk : ecount;
    for (int i = start + t; i < end; i += 256)
        atomicAdd(&hist[edst[i] >> 8], 1);          // LDS
    __syncthreads();
    for (int bk = t; bk < 512; bk += 256) {
        int h = hist[bk];
        base[bk] = h ? atomicAdd(&gCur[bk], h) : 0; // global, 1 per (block,bucket)
        hist[bk] = 0;
    }
    __syncthreads();
    for (int i = start + t; i < end; i += 256) {
        int d = edst[i];
        int b = d >> 8;
        int slot = atomicAdd(&hist[b], 1);          // LDS
        int pos = base[b] + slot;
        if (pos < cap)
            ebuf[(size_t)b * cap + pos] = make_int2(esrc[i], d);
    }
}

__global__ __launch_bounds__(512) void k_scanb(const int* __restrict__ gCur,
    int* __restrict__ bBase, int* __restrict__ row_ptr, int nbuck, int n, int ecount)
{
    __shared__ int sm[512];
    int t = threadIdx.x;
    int c = (t < nbuck) ? gCur[t] : 0;
    sm[t] = c;
    __syncthreads();
    for (int d = 1; d < 512; d <<= 1) {
        int v = (t >= d) ? sm[t - d] : 0;
        __syncthreads();
        sm[t] += v;
        __syncthreads();
    }
    if (t < nbuck) bBase[t] = sm[t] - c;
    if (t == 0) row_ptr[n] = ecount;
}

__global__ __launch_bounds__(256) void k_bcsr(const int2* __restrict__ ebuf,
    const int* __restrict__ gCur, const int* __restrict__ bBase,
    int* __restrict__ row_ptr, int* __restrict__ col, int cap, int n)
{
    __shared__ int h[256];
    __shared__ int sm[256];
    int b = blockIdx.x, t = threadIdx.x;
    int cnt = gCur[b];
    int nb0 = b << 8;
    const int2* eb = ebuf + (size_t)b * cap;
    h[t] = 0;
    __syncthreads();
    for (int i = t; i < cnt; i += 256)
        atomicAdd(&h[eb[i].y & 255], 1);            // LDS histogram
    __syncthreads();
    int hv = h[t];
    sm[t] = hv;
    __syncthreads();
    for (int d = 1; d < 256; d <<= 1) {
        int v = (t >= d) ? sm[t - d] : 0;
        __syncthreads();
        sm[t] += v;
        __syncthreads();
    }
    int excl = sm[t] - hv;
    int gb = bBase[b];
    int g = nb0 + t;
    if (g < n) row_ptr[g] = gb + excl;
    __syncthreads();
    h[t] = excl;                                    // reuse as cursor
    __syncthreads();
    for (int i = t; i < cnt; i += 256) {
        int2 e = eb[i];
        int slot = atomicAdd(&h[e.y & 255], 1);     // LDS
        col[gb + slot] = e.x;
    }
}

// ---------------- mean aggregation (bf16): quarter-wave per edge ----------------
__global__ __launch_bounds__(256) void k_agg(
    const unsigned short* __restrict__ xh, unsigned short* __restrict__ mh, int SK,
    const int* __restrict__ row_ptr, const int* __restrict__ col, int n,
    int zr, int emax)
{
    int lane = threadIdx.x & 63;
    int qw  = lane >> 4;
    int l16 = lane & 15;
    int node = blockIdx.x * 4 + (threadIdx.x >> 6);
    if (node >= n) return;
    node = __builtin_amdgcn_readfirstlane(node);
    int s = row_ptr[node], e = row_ptr[node + 1];
    int deg = e - s;
    float a0 = 0.f, a1 = 0.f, a2 = 0.f, a3 = 0.f;
    float a4 = 0.f, a5 = 0.f, a6 = 0.f, a7 = 0.f;
    size_t cOff = (size_t)l16 * 8;        // 8 bf16 cols per lane

    auto accum = [&](uint4 r) {
        a0 += __builtin_bit_cast(float, r.x << 16);
        a1 += __builtin_bit_cast(float, r.x & 0xffff0000u);
        a2 += __builtin_bit_cast(float, r.y << 16);
        a3 += __builtin_bit_cast(float, r.y & 0xffff0000u);
        a4 += __builtin_bit_cast(float, r.z << 16);
        a5 += __builtin_bit_cast(float, r.z & 0xffff0000u);
        a6 += __builtin_bit_cast(float, r.w << 16);
        a7 += __builtin_bit_cast(float, r.w & 0xffff0000u);
    };

    int em1 = emax - 1;
    for (int p = s + qw; p < e; p += 16) {
        int p1 = p + 4, p2 = p + 8, p3 = p + 12;
        int q1 = p1 < em1 ? p1 : em1;
        int q2 = p2 < em1 ? p2 : em1;
        int q3 = p3 < em1 ? p3 : em1;
        int t0 = col[p];
        int t1 = col[q1];
        int t2 = col[q2];
        int t3 = col[q3];
        int c0 = t0;
        int c1 = (p1 < e) ? t1 : zr;
        int c2 = (p2 < e) ? t2 : zr;
        int c3 = (p3 < e) ? t3 : zr;
        uint4 r0 = *(const uint4*)(xh + (size_t)c0 * SK + cOff);
        uint4 r1 = *(const uint4*)(xh + (size_t)c1 * SK + cOff);
        uint4 r2 = *(const uint4*)(xh + (size_t)c2 * SK + cOff);
        uint4 r3 = *(const uint4*)(xh + (size_t)c3 * SK + cOff);
        accum(r0); accum(r1); accum(r2); accum(r3);
    }

    a0 += __shfl_xor(a0, 16); a0 += __shfl_xor(a0, 32);
    a1 += __shfl_xor(a1, 16); a1 += __shfl_xor(a1, 32);
    a2 += __shfl_xor(a2, 16); a2 += __shfl_xor(a2, 32);
    a3 += __shfl_xor(a3, 16); a3 += __shfl_xor(a3, 32);
    a4 += __shfl_xor(a4, 16); a4 += __shfl_xor(a4, 32);
    a5 += __shfl_xor(a5, 16); a5 += __shfl_xor(a5, 32);
    a6 += __shfl_xor(a6, 16); a6 += __shfl_xor(a6, 32);
    a7 += __shfl_xor(a7, 16); a7 += __shfl_xor(a7, 32);

    if (qw == 0) {
        float inv = 1.f / (float)(deg > 1 ? deg : 1);
        uint4 o;
        o.x = (unsigned int)f2bf(a0 * inv) | ((unsigned int)f2bf(a1 * inv) << 16);
        o.y = (unsigned int)f2bf(a2 * inv) | ((unsigned int)f2bf(a3 * inv) << 16);
        o.z = (unsigned int)f2bf(a4 * inv) | ((unsigned int)f2bf(a5 * inv) << 16);
        o.w = (unsigned int)f2bf(a6 * inv) | ((unsigned int)f2bf(a7 * inv) << 16);
        *(uint4*)(mh + (size_t)node * SK + cOff) = o;
    }
}

// ---------------- split-weight bf16-activation MFMA GEMM, M-tile=64, block=256 ----------------
// (r14's M=32 reverted: +occupancy didn't pay for doubled W traffic/fixed cost)
// A row-major bf16 [m][SK], SK = KT8*32.  Weights split hi/lo.
// K-loop (#pragma unroll 1): per k-tile load ah,bh,bl once; groups Ah·Wh, Ah·Wl.
// Epilogue in 2 phases of 32 rows, 8 threads/row.
// EPI 0: out = relu(C+bias) -> bf16 store.
// EPI 1: LN+relu, out = res + 0.5*r -> bf16 store.
// EPI 3: conv2+head fused: LN+relu+res -> bf16 x2 into LDS Xs, then head GEMM
//        from LDS (x2 @ wh1 hi/lo, relu+bh1, ·wh2) -> outp fp32.  No x2 store.
template<int NC, int KT8, int EPI>
__global__ __launch_bounds__(256) void k_gemm(
    const unsigned short* __restrict__ A, int SK,
    const unsigned short* __restrict__ Whi, const unsigned short* __restrict__ Wlo,
    const float* __restrict__ bias,
    const float* __restrict__ g, const float* __restrict__ be,
    const unsigned short* __restrict__ Src, int SSK,
    unsigned short* __restrict__ Dst, int DSK,
    const unsigned short* __restrict__ Hh, const unsigned short* __restrict__ Hl,
    const float* __restrict__ bh1p,
    const float* __restrict__ wh2, const float* __restrict__ bh2, float* __restrict__ outp,
    int n)
{
    constexpr int NT = NC / 64;       // n-16-tiles per wave
    __shared__ float Cb[32][NC + 4];
    __shared__ unsigned short Xs[(EPI == 3) ? 32 : 1][(EPI == 3) ? 132 : 1];
    __shared__ float hq[(EPI == 3) ? 4 : 1][(EPI == 3) ? 32 : 1];
    int t = threadIdx.x;
    int lane = t & 63, w = t >> 6;
    int l15 = lane & 15, kg = lane >> 4;
    int m0 = blockIdx.x * 64;

    size_t aoff[4];
    #pragma unroll
    for (int mt = 0; mt < 4; ++mt) {
        int r = m0 + mt * 16 + l15;
        r = r < n ? r : n - 1;
        aoff[mt] = (size_t)r * SK + kg * 8;
    }
    size_t nb[NT];
    #pragma unroll
    for (int nt = 0; nt < NT; ++nt)
        nb[nt] = (size_t)(w * (NC / 4) + nt * 16 + l15) * 32 + kg * 8;

    f32x4 acc[4][NT];
    #pragma unroll
    for (int mt = 0; mt < 4; ++mt)
        #pragma unroll
        for (int nt = 0; nt < NT; ++nt)
            acc[mt][nt] = (f32x4)(0.f);

    #pragma unroll 1
    for (int s = 0; s < KT8; ++s) {
        int koff = s * 32;
        short8 ah[4];
        #pragma unroll
        for (int mt = 0; mt < 4; ++mt)
            ah[mt] = *(const short8*)(A + aoff[mt] + koff);
        short8 bh[NT], bl[NT];
        #pragma unroll
        for (int nt = 0; nt < NT; ++nt) {
            bh[nt] = *(const short8*)(Whi + (size_t)s * NC * 32 + nb[nt]);
            bl[nt] = *(const short8*)(Wlo + (size_t)s * NC * 32 + nb[nt]);
        }
        #pragma unroll
        for (int mt = 0; mt < 4; ++mt)
            #pragma unroll
            for (int nt = 0; nt < NT; ++nt)
                acc[mt][nt] = __builtin_amdgcn_mfma_f32_16x16x32_bf16(ah[mt], bh[nt], acc[mt][nt], 0, 0, 0);
        #pragma unroll
        for (int mt = 0; mt < 4; ++mt)
            #pragma unroll
            for (int nt = 0; nt < NT; ++nt)
                acc[mt][nt] = __builtin_amdgcn_mfma_f32_16x16x32_bf16(ah[mt], bl[nt], acc[mt][nt], 0, 0, 0);
    }

    // Epilogue: two phases of 32 rows.  C/D layout: col = lane&15, row = quad*4 + reg.
    constexpr int CW = NC / 8;        // cols per epilogue thread (8 threads/row)
    int er = t >> 3, q = t & 7;
    int cb = q * CW;

    #pragma unroll
    for (int p = 0; p < 2; ++p) {
        if (p) __syncthreads();       // phase-0 readers done before overwrite
        #pragma unroll
        for (int mt2 = 0; mt2 < 2; ++mt2) {
            int mt = 2 * p + mt2;
            #pragma unroll
            for (int nt = 0; nt < NT; ++nt)
                #pragma unroll
                for (int r = 0; r < 4; ++r)
                    Cb[mt2 * 16 + kg * 4 + r][w * (NC / 4) + nt * 16 + l15] = acc[mt][nt][r];
        }
        __syncthreads();

        int gr = m0 + p * 32 + er;

        if (EPI == 0) {
            if (gr < n) {
                #pragma unroll
                for (int i = 0; i < CW / 4; ++i) {
                    int c = cb + 4 * i;
                    float4 v  = *(const float4*)&Cb[er][c];
                    float4 bi = *(const float4*)&bias[c];
                    ushort4 hv = make_ushort4(f2bf(fmaxf(v.x + bi.x, 0.f)),
                                              f2bf(fmaxf(v.y + bi.y, 0.f)),
                                              f2bf(fmaxf(v.z + bi.z, 0.f)),
                                              f2bf(fmaxf(v.w + bi.w, 0.f)));
                    *(ushort4*)(Dst + (size_t)gr * DSK + c) = hv;
                }
            }
        } else {
            // EPI 1 / 3: LayerNorm + relu + residual
            float s = 0.f, ss = 0.f;
            #pragma unroll
            for (int i = 0; i < CW / 4; ++i) {
                int c = cb + 4 * i;
                float4 v  = *(const float4*)&Cb[er][c];
                float4 bi = *(const float4*)&bias[c];
                float a0 = v.x + bi.x, a1 = v.y + bi.y, a2 = v.z + bi.z, a3 = v.w + bi.w;
                s  += a0 + a1 + a2 + a3;
                ss += a0 * a0 + a1 * a1 + a2 * a2 + a3 * a3;
            }
            s  += __shfl_xor(s, 1);  s  += __shfl_xor(s, 2);  s  += __shfl_xor(s, 4);
            ss += __shfl_xor(ss, 1); ss += __shfl_xor(ss, 2); ss += __shfl_xor(ss, 4);
            float mu  = s * (1.f / NC);
            float var = ss * (1.f / NC) - mu * mu;
            float rs  = rsqrtf(var + 1e-5f);
            int rl = gr < n ? gr : n - 1;     // EPI 3 writes Xs for all rows (clamped)
            if (EPI == 3 || gr < n) {
                #pragma unroll
                for (int i = 0; i < CW / 4; ++i) {
                    int c = cb + 4 * i;
                    float4 v  = *(const float4*)&Cb[er][c];
                    float4 bi = *(const float4*)&bias[c];
                    float4 gg = *(const float4*)&g[c];
                    float4 bb = *(const float4*)&be[c];
                    float r0 = fmaxf((v.x + bi.x - mu) * rs * gg.x + bb.x, 0.f);
                    float r1 = fmaxf((v.y + bi.y - mu) * rs * gg.y + bb.y, 0.f);
                    float r2 = fmaxf((v.z + bi.z - mu) * rs * gg.z + bb.z, 0.f);
                    float r3 = fmaxf((v.w + bi.w - mu) * rs * gg.w + bb.w, 0.f);
                    ushort4 rh = *(const ushort4*)(Src + (size_t)rl * SSK + c);
                    ushort4 hv = make_ushort4(f2bf(bf2f(rh.x) + 0.5f * r0),
                                              f2bf(bf2f(rh.y) + 0.5f * r1),
                                              f2bf(bf2f(rh.z) + 0.5f * r2),
                                              f2bf(bf2f(rh.w) + 0.5f * r3));
                    if (EPI == 3)
                        *(ushort4*)&Xs[er][c] = hv;
                    else
                        *(ushort4*)(Dst + (size_t)gr * DSK + c) = hv;
                }
            }
        }

        if (EPI == 3) {
            __syncthreads();          // Xs complete before fragment reads
            // head GEMM from LDS: Xs(32 x NC) @ wh1(NC x 64) split hi/lo.
            // wave w owns 16 output cols [w*16, w*16+16); mt 0..1 cover the 32 rows.
            f32x4 hacc[2];
            hacc[0] = (f32x4)(0.f);
            hacc[1] = (f32x4)(0.f);
            #pragma unroll
            for (int kt = 0; kt < NC / 32; ++kt) {
                short8 af[2];
                #pragma unroll
                for (int mt = 0; mt < 2; ++mt)
                    af[mt] = *(const short8*)&Xs[mt * 16 + l15][kt * 32 + kg * 8];
                size_t ho = ((size_t)kt * 64 + w * 16 + l15) * 32 + kg * 8;
                short8 bhh = *(const short8*)(Hh + ho);
                short8 bhl = *(const short8*)(Hl + ho);
                #pragma unroll
                for (int mt = 0; mt < 2; ++mt)
                    hacc[mt] = __builtin_amdgcn_mfma_f32_16x16x32_bf16(af[mt], bhh, hacc[mt], 0, 0, 0);
                #pragma unroll
                for (int mt = 0; mt < 2; ++mt)
                    hacc[mt] = __builtin_amdgcn_mfma_f32_16x16x32_bf16(af[mt], bhl, hacc[mt], 0, 0, 0);
            }
            float b1v = bh1p[w * 16 + l15];
            float w2v = wh2[w * 16 + l15];
            #pragma unroll
            for (int mt = 0; mt < 2; ++mt)
                #pragma unroll
                for (int r = 0; r < 4; ++r) {
                    float part = fmaxf(hacc[mt][r] + b1v, 0.f) * w2v;
                    part += __shfl_xor(part, 1);
                    part += __shfl_xor(part, 2);
                    part += __shfl_xor(part, 4);
                    part += __shfl_xor(part, 8);
                    if (l15 == 0) hq[w][mt * 16 + kg * 4 + r] = part;
                }
            __syncthreads();
            if (t < 32) {
                int gr2 = m0 + p * 32 + t;
                if (gr2 < n)
                    outp[gr2] = hq[0][t] + hq[1][t] + hq[2][t] + hq[3][t] + bh2[0];
            }
        }
    }
}

// ---------------- launcher ----------------
extern "C" void kernel_launch(void* const* d_in, const int* in_sizes, int n_in,
                              void* d_out, int out_size, void* d_ws, size_t ws_size,
                              hipStream_t stream)
{
    const float* xnum = (const float*)d_in[0];
    const int*   xcat = (const int*)d_in[1];
    const int*   eidx = (const int*)d_in[2];
    const float* e0   = (const float*)d_in[3];
    const float* e1   = (const float*)d_in[4];
    const float* e2   = (const float*)d_in[5];
    const float* e3   = (const float*)d_in[6];
    const float* w_in = (const float*)d_in[7];
    const float* b_in = (const float*)d_in[8];
    const float* w1l  = (const float*)d_in[9];
    const float* b1l  = (const float*)d_in[10];
    const float* w1r  = (const float*)d_in[11];
    const float* w2l  = (const float*)d_in[12];
    const float* b2l  = (const float*)d_in[13];
    const float* w2r  = (const float*)d_in[14];
    const float* g1   = (const float*)d_in[15];
    const float* be1  = (const float*)d_in[16];
    const float* g2   = (const float*)d_in[17];
    const float* be2  = (const float*)d_in[18];
    const float* wh1  = (const float*)d_in[19];
    const float* bh1  = (const float*)d_in[20];
    const float* wh2  = (const float*)d_in[21];
    const float* bh2  = (const float*)d_in[22];

    int n = in_sizes[0] / 32;
    int ecount = in_sizes[2] / 2;
    const int* esrc = eidx;
    const int* edst = eidx + ecount;

    char* ws = (char*)d_ws;
    size_t off = 0;
    auto alloc = [&](size_t bytes) -> void* {
        void* p = ws + off;
        off += (bytes + 255) & ~(size_t)255;
        return p;
    };
    // A1: (n+1) x 256 bf16 = [mean1(128) | x0(128)]; row n = zero row for agg redirect.
    // A2: (n+1) x 256 = [mean2 | x1]; A0 (n x 96) aliases A2.  No x2 buffer (head fused).
    unsigned short* A1 = (unsigned short*)alloc((size_t)(n + 1) * 256 * 2);
    unsigned short* A2 = (unsigned short*)alloc((size_t)(n + 1) * 256 * 2);
    unsigned short* A0 = A2;
    // Weight fragment buffers (hi/lo split)
    unsigned short* w0h = (unsigned short*)alloc((size_t)96 * 128 * 2);
    unsigned short* w0l = (unsigned short*)alloc((size_t)96 * 128 * 2);
    unsigned short* w1h = (unsigned short*)alloc((size_t)256 * 128 * 2);
    unsigned short* w1lo= (unsigned short*)alloc((size_t)256 * 128 * 2);
    unsigned short* w2h = (unsigned short*)alloc((size_t)256 * 128 * 2);
    unsigned short* w2lo= (unsigned short*)alloc((size_t)256 * 128 * 2);
    unsigned short* whh = (unsigned short*)alloc((size_t)128 * 64 * 2);
    unsigned short* whl = (unsigned short*)alloc((size_t)128 * 64 * 2);
    // CSR via bucketed counting sort
    int nbuck = (n + 255) >> 8;
    int cap = ecount / nbuck + ecount / (2 * nbuck) + 256;   // mean + 50% + slack
    int* gCur    = (int*)alloc(512 * 4);
    int* bBase   = (int*)alloc(512 * 4);
    int* row_ptr = (int*)alloc((size_t)(n + 1) * 4);
    int* col     = (int*)alloc((size_t)ecount * 4);
    int2* ebuf   = (int2*)alloc((size_t)nbuck * cap * 8);
    (void)ws_size; (void)n_in; (void)out_size;

    int gemmBlocks = (n + 63) / 64;
    int aggBlocks = (n + 3) / 4;

    // merged weight prep + zero-row + gCur init (one dispatch, no memsets)
    k_prep<<<337, 256, 0, stream>>>(
        w_in, w1l, w1r, w2l, w2r, wh1,
        w0h, w0l, w1h, w1lo, w2h, w2lo, whh, whl,
        A1 + (size_t)n * 256, A2 + (size_t)n * 256, gCur);

    // input features -> A0 (bf16, 96 cols)
    k_stack0<<<((size_t)n * 6 + 255) / 256, 256, 0, stream>>>(xnum, xcat, e0, e1, e2, e3, A0, n);

    // CSR build: partition -> bucket scan -> per-bucket CSR
    int nblkP = 512;
    int chunk = (ecount + nblkP - 1) / nblkP;
    k_part<<<nblkP, 256, 0, stream>>>(esrc, edst, gCur, ebuf, ecount, chunk, cap);
    k_scanb<<<1, 512, 0, stream>>>(gCur, bBase, row_ptr, nbuck, n, ecount);
    k_bcsr<<<nbuck, 256, 0, stream>>>(ebuf, gCur, bBase, row_ptr, col, cap, n);

    // input MLP: A0[96] @ W0 -> x0 bf16 -> A1 x-slot (cols 128..255)
    k_gemm<128, 3, 0><<<gemmBlocks, 256, 0, stream>>>(
        A0, 96, w0h, w0l, b_in,
        nullptr, nullptr, nullptr, 0,
        A1 + 128, 256,
        nullptr, nullptr, nullptr, nullptr, nullptr, nullptr, n);

    // conv1: mean of x0 -> A1 cols 0..127; GEMM A1[256] @ [w1l;w1r] -> x1 -> A2 x-slot
    k_agg<<<aggBlocks, 256, 0, stream>>>(A1 + 128, A1, 256, row_ptr, col, n, n, ecount);
    k_gemm<128, 8, 1><<<gemmBlocks, 256, 0, stream>>>(
        A1, 256, w1h, w1lo, b1l,
        g1, be1, A1 + 128, 256,
        A2 + 128, 256,
        nullptr, nullptr, nullptr, nullptr, nullptr, nullptr, n);

    // conv2 + head fused: mean of x1 -> A2 cols 0..127; GEMM A2[256] -> x2 (LDS only)
    // -> head -> out fp32
    k_agg<<<aggBlocks, 256, 0, stream>>>(A2 + 128, A2, 256, row_ptr, col, n, n, ecount);
    k_gemm<128, 8, 3><<<gemmBlocks, 256, 0, stream>>>(
        A2, 256, w2h, w2lo, b2l,
        g2, be2, A2 + 128, 256,
        nullptr, 0,
        whh, whl, bh1, wh2, bh2, (float*)d_out, n);
}

// Round 16
// 437.229 us; speedup vs baseline: 1.0379x; 1.0125x over previous
//
#include <hip/hip_runtime.h>

#define HID 128

typedef __attribute__((ext_vector_type(8))) short short8;
typedef __attribute__((ext_vector_type(4))) float f32x4;

__device__ __forceinline__ float bf2f(unsigned short u) {
    unsigned int x = ((unsigned int)u) << 16;
    return __builtin_bit_cast(float, x);
}
__device__ __forceinline__ unsigned short f2bf(float f) {
    unsigned int u = __builtin_bit_cast(unsigned int, f);
    u += 0x7fffu + ((u >> 16) & 1u);
    return (unsigned short)(u >> 16);
}

// fp32 [K,N] (optionally two stacked sources) -> fragment layout hi/lo:
// elem (k,n) at ((k/32)*N + n)*32 + k%32
__device__ __forceinline__ void prep_one(const float* __restrict__ s1, int k1,
    const float* __restrict__ s2, int N, int i,
    unsigned short* __restrict__ whi, unsigned short* __restrict__ wlo)
{
    int k = i / N, nn = i - k * N;
    float v = (k < k1) ? s1[(size_t)k * N + nn]
                       : (s2 ? s2[(size_t)(k - k1) * N + nn] : 0.f);
    unsigned short h = f2bf(v);
    unsigned short l = f2bf(v - bf2f(h));
    size_t o = ((size_t)(k >> 5) * N + nn) * 32 + (k & 31);
    whi[o] = h; wlo[o] = l;
}

// ---------------- merged prep: all 4 weight preps + zero-row/gCur init, one dispatch ----------------
// blocks [0,48): w_in (96x128)   [48,176): w1 (256x128)   [176,304): w2 (256x128)
// [304,336): wh1 (128x64)        336: zero rows z1,z2 (256 shorts each) + gCur (512 ints)
__global__ __launch_bounds__(256) void k_prep(
    const float* __restrict__ w_in, const float* __restrict__ w1l,
    const float* __restrict__ w1r, const float* __restrict__ w2l,
    const float* __restrict__ w2r, const float* __restrict__ wh1,
    unsigned short* __restrict__ w0h, unsigned short* __restrict__ w0l,
    unsigned short* __restrict__ w1h, unsigned short* __restrict__ w1lo,
    unsigned short* __restrict__ w2h, unsigned short* __restrict__ w2lo,
    unsigned short* __restrict__ whh, unsigned short* __restrict__ whl,
    unsigned short* __restrict__ z1, unsigned short* __restrict__ z2,
    int* __restrict__ gCur)
{
    int b = blockIdx.x, t = threadIdx.x;
    if (b < 48) {
        prep_one(w_in, 71, nullptr, 128, b * 256 + t, w0h, w0l);
    } else if (b < 176) {
        prep_one(w1l, 128, w1r, 128, (b - 48) * 256 + t, w1h, w1lo);
    } else if (b < 304) {
        prep_one(w2l, 128, w2r, 128, (b - 176) * 256 + t, w2h, w2lo);
    } else if (b < 336) {
        prep_one(wh1, 128, nullptr, 64, (b - 304) * 256 + t, whh, whl);
    } else {
        z1[t] = 0; z2[t] = 0;
        gCur[t] = 0; gCur[t + 256] = 0;
    }
}

// ---------------- input feature prestack: [xnum | emb0..3 | pad] -> bf16,
// A0 row-major [n][96].  6 chunks of 16 cols per row. ----------------
__global__ __launch_bounds__(256) void k_stack0(
    const float* __restrict__ xnum, const int* __restrict__ xcat,
    const float* __restrict__ e0, const float* __restrict__ e1,
    const float* __restrict__ e2, const float* __restrict__ e3,
    unsigned short* __restrict__ A0, int n)
{
    int g = blockIdx.x * 256 + threadIdx.x;
    int r = g / 6, c = g - r * 6;              // 6 chunks of 16 cols (96 features)
    if (r >= n) return;
    int4 cc = ((const int4*)xcat)[r];
    float v[16];
    int base = c * 16;
    #pragma unroll
    for (int j = 0; j < 16; ++j) {
        int col = base + j;
        float val;
        if      (col < 32) val = xnum[(size_t)r * 32 + col];
        else if (col < 42) val = e0[(size_t)cc.x * 10 + (col - 32)];
        else if (col < 48) val = e1[(size_t)cc.y * 6  + (col - 42)];
        else if (col < 53) val = e2[(size_t)cc.z * 5  + (col - 48)];
        else if (col < 71) val = e3[(size_t)cc.w * 18 + (col - 53)];
        else               val = 0.f;
        v[j] = val;
    }
    unsigned int ph[8];
    #pragma unroll
    for (int j = 0; j < 8; ++j)
        ph[j] = (unsigned int)f2bf(v[2*j]) | ((unsigned int)f2bf(v[2*j+1]) << 16);
    unsigned int* dh = (unsigned int*)(A0 + (size_t)r * 96 + base);
    uint4 a; a.x = ph[0]; a.y = ph[1]; a.z = ph[2]; a.w = ph[3];
    uint4 b; b.x = ph[4]; b.y = ph[5]; b.z = ph[6]; b.w = ph[7];
    ((uint4*)dh)[0] = a; ((uint4*)dh)[1] = b;
}

// ---------------- CSR build via bucketed counting sort (LDS atomics) ----------------
__global__ __launch_bounds__(256) void k_part(const int* __restrict__ esrc,
    const int* __restrict__ edst, int* __restrict__ gCur, int2* __restrict__ ebuf,
    int ecount, int chunk, int cap)
{
    __shared__ int hist[512];
    __shared__ int base[512];
    int t = threadIdx.x;
    hist[t] = 0; hist[t + 256] = 0;
    __syncthreads();
    int start = blockIdx.x * chunk;
    int end = start + chunk < ecount ? start + chunk : ecount;
    for (int i = start + t; i < end; i += 256)
        atomicAdd(&hist[edst[i] >> 8], 1);          // LDS
    __syncthreads();
    for (int bk = t; bk < 512; bk += 256) {
        int h = hist[bk];
        base[bk] = h ? atomicAdd(&gCur[bk], h) : 0; // global, 1 per (block,bucket)
        hist[bk] = 0;
    }
    __syncthreads();
    for (int i = start + t; i < end; i += 256) {
        int d = edst[i];
        int b = d >> 8;
        int slot = atomicAdd(&hist[b], 1);          // LDS
        int pos = base[b] + slot;
        if (pos < cap)
            ebuf[(size_t)b * cap + pos] = make_int2(esrc[i], d);
    }
}

__global__ __launch_bounds__(512) void k_scanb(const int* __restrict__ gCur,
    int* __restrict__ bBase, int* __restrict__ row_ptr, int nbuck, int n, int ecount)
{
    __shared__ int sm[512];
    int t = threadIdx.x;
    int c = (t < nbuck) ? gCur[t] : 0;
    sm[t] = c;
    __syncthreads();
    for (int d = 1; d < 512; d <<= 1) {
        int v = (t >= d) ? sm[t - d] : 0;
        __syncthreads();
        sm[t] += v;
        __syncthreads();
    }
    if (t < nbuck) bBase[t] = sm[t] - c;
    if (t == 0) row_ptr[n] = ecount;
}

__global__ __launch_bounds__(256) void k_bcsr(const int2* __restrict__ ebuf,
    const int* __restrict__ gCur, const int* __restrict__ bBase,
    int* __restrict__ row_ptr, int* __restrict__ col, int cap, int n)
{
    __shared__ int h[256];
    __shared__ int sm[256];
    int b = blockIdx.x, t = threadIdx.x;
    int cnt = gCur[b];
    int nb0 = b << 8;
    const int2* eb = ebuf + (size_t)b * cap;
    h[t] = 0;
    __syncthreads();
    for (int i = t; i < cnt; i += 256)
        atomicAdd(&h[eb[i].y & 255], 1);            // LDS histogram
    __syncthreads();
    int hv = h[t];
    sm[t] = hv;
    __syncthreads();
    for (int d = 1; d < 256; d <<= 1) {
        int v = (t >= d) ? sm[t - d] : 0;
        __syncthreads();
        sm[t] += v;
        __syncthreads();
    }
    int excl = sm[t] - hv;
    int gb = bBase[b];
    int g = nb0 + t;
    if (g < n) row_ptr[g] = gb + excl;
    __syncthreads();
    h[t] = excl;                                    // reuse as cursor
    __syncthreads();
    for (int i = t; i < cnt; i += 256) {
        int2 e = eb[i];
        int slot = atomicAdd(&h[e.y & 255], 1);     // LDS
        col[gb + slot] = e.x;
    }
}

// ---------------- mean aggregation (bf16): quarter-wave per edge ----------------
// 16 lanes x uint4 cover a 256 B row; ALWAYS 4 gathers in flight — out-of-range
// edges redirect to zero row `zr` (branchless, address-clamped col loads).
__global__ __launch_bounds__(256) void k_agg(
    const unsigned short* __restrict__ xh, unsigned short* __restrict__ mh, int SK,
    const int* __restrict__ row_ptr, const int* __restrict__ col, int n,
    int zr, int emax)
{
    int lane = threadIdx.x & 63;
    int qw  = lane >> 4;
    int l16 = lane & 15;
    int node = blockIdx.x * 4 + (threadIdx.x >> 6);
    if (node >= n) return;
    node = __builtin_amdgcn_readfirstlane(node);
    int s = row_ptr[node], e = row_ptr[node + 1];
    int deg = e - s;
    float a0 = 0.f, a1 = 0.f, a2 = 0.f, a3 = 0.f;
    float a4 = 0.f, a5 = 0.f, a6 = 0.f, a7 = 0.f;
    size_t cOff = (size_t)l16 * 8;        // 8 bf16 cols per lane

    auto accum = [&](uint4 r) {
        a0 += __builtin_bit_cast(float, r.x << 16);
        a1 += __builtin_bit_cast(float, r.x & 0xffff0000u);
        a2 += __builtin_bit_cast(float, r.y << 16);
        a3 += __builtin_bit_cast(float, r.y & 0xffff0000u);
        a4 += __builtin_bit_cast(float, r.z << 16);
        a5 += __builtin_bit_cast(float, r.z & 0xffff0000u);
        a6 += __builtin_bit_cast(float, r.w << 16);
        a7 += __builtin_bit_cast(float, r.w & 0xffff0000u);
    };

    int em1 = emax - 1;
    for (int p = s + qw; p < e; p += 16) {
        int p1 = p + 4, p2 = p + 8, p3 = p + 12;
        int q1 = p1 < em1 ? p1 : em1;
        int q2 = p2 < em1 ? p2 : em1;
        int q3 = p3 < em1 ? p3 : em1;
        int t0 = col[p];
        int t1 = col[q1];
        int t2 = col[q2];
        int t3 = col[q3];
        int c0 = t0;
        int c1 = (p1 < e) ? t1 : zr;
        int c2 = (p2 < e) ? t2 : zr;
        int c3 = (p3 < e) ? t3 : zr;
        uint4 r0 = *(const uint4*)(xh + (size_t)c0 * SK + cOff);
        uint4 r1 = *(const uint4*)(xh + (size_t)c1 * SK + cOff);
        uint4 r2 = *(const uint4*)(xh + (size_t)c2 * SK + cOff);
        uint4 r3 = *(const uint4*)(xh + (size_t)c3 * SK + cOff);
        accum(r0); accum(r1); accum(r2); accum(r3);
    }

    a0 += __shfl_xor(a0, 16); a0 += __shfl_xor(a0, 32);
    a1 += __shfl_xor(a1, 16); a1 += __shfl_xor(a1, 32);
    a2 += __shfl_xor(a2, 16); a2 += __shfl_xor(a2, 32);
    a3 += __shfl_xor(a3, 16); a3 += __shfl_xor(a3, 32);
    a4 += __shfl_xor(a4, 16); a4 += __shfl_xor(a4, 32);
    a5 += __shfl_xor(a5, 16); a5 += __shfl_xor(a5, 32);
    a6 += __shfl_xor(a6, 16); a6 += __shfl_xor(a6, 32);
    a7 += __shfl_xor(a7, 16); a7 += __shfl_xor(a7, 32);

    if (qw == 0) {
        float inv = 1.f / (float)(deg > 1 ? deg : 1);
        uint4 o;
        o.x = (unsigned int)f2bf(a0 * inv) | ((unsigned int)f2bf(a1 * inv) << 16);
        o.y = (unsigned int)f2bf(a2 * inv) | ((unsigned int)f2bf(a3 * inv) << 16);
        o.z = (unsigned int)f2bf(a4 * inv) | ((unsigned int)f2bf(a5 * inv) << 16);
        o.w = (unsigned int)f2bf(a6 * inv) | ((unsigned int)f2bf(a7 * inv) << 16);
        *(uint4*)(mh + (size_t)node * SK + cOff) = o;
    }
}

// ---------------- split-weight bf16-activation MFMA GEMM, M-tile=64, block=256 ----------------
// Best-known config (r13, 431 us): r12 manual prefetch, r14 M=32, r15 LDS head-fusion
// all regressed — this K-loop shape is at its plateau (cf. m131-m141).
// A row-major bf16 [m][SK], SK = KT8*32.  Weights split hi/lo.
// K-loop (#pragma unroll 1): per k-tile load ah,bh,bl once; groups Ah·Wh, Ah·Wl.
// Epilogue in 2 phases of 32 rows (LDS 16.9 KB), 8 threads/row.
// EPI 0: out = relu(C+bias) -> bf16 store.  EPI 1: LN+relu, out = res + 0.5*r -> bf16 store.
// EPI 2: head: s = relu(C+bias)·wh2 + bh2 -> outp.
template<int NC, int KT8, int EPI>
__global__ __launch_bounds__(256) void k_gemm(
    const unsigned short* __restrict__ A, int SK,
    const unsigned short* __restrict__ Whi, const unsigned short* __restrict__ Wlo,
    const float* __restrict__ bias,
    const float* __restrict__ g, const float* __restrict__ be,
    const unsigned short* __restrict__ Src, int SSK,
    unsigned short* __restrict__ Dst, int DSK,
    const float* __restrict__ wh2, const float* __restrict__ bh2, float* __restrict__ outp,
    int n)
{
    constexpr int NT = NC / 64;       // n-16-tiles per wave
    __shared__ float Cb[32][NC + 4];
    int t = threadIdx.x;
    int lane = t & 63, w = t >> 6;
    int l15 = lane & 15, kg = lane >> 4;
    int m0 = blockIdx.x * 64;

    size_t aoff[4];
    #pragma unroll
    for (int mt = 0; mt < 4; ++mt) {
        int r = m0 + mt * 16 + l15;
        r = r < n ? r : n - 1;
        aoff[mt] = (size_t)r * SK + kg * 8;
    }
    size_t nb[NT];
    #pragma unroll
    for (int nt = 0; nt < NT; ++nt)
        nb[nt] = (size_t)(w * (NC / 4) + nt * 16 + l15) * 32 + kg * 8;

    f32x4 acc[4][NT];
    #pragma unroll
    for (int mt = 0; mt < 4; ++mt)
        #pragma unroll
        for (int nt = 0; nt < NT; ++nt)
            acc[mt][nt] = (f32x4)(0.f);

    #pragma unroll 1
    for (int s = 0; s < KT8; ++s) {
        int koff = s * 32;
        short8 ah[4];
        #pragma unroll
        for (int mt = 0; mt < 4; ++mt)
            ah[mt] = *(const short8*)(A + aoff[mt] + koff);
        short8 bh[NT], bl[NT];
        #pragma unroll
        for (int nt = 0; nt < NT; ++nt) {
            bh[nt] = *(const short8*)(Whi + (size_t)s * NC * 32 + nb[nt]);
            bl[nt] = *(const short8*)(Wlo + (size_t)s * NC * 32 + nb[nt]);
        }
        #pragma unroll
        for (int mt = 0; mt < 4; ++mt)
            #pragma unroll
            for (int nt = 0; nt < NT; ++nt)
                acc[mt][nt] = __builtin_amdgcn_mfma_f32_16x16x32_bf16(ah[mt], bh[nt], acc[mt][nt], 0, 0, 0);
        #pragma unroll
        for (int mt = 0; mt < 4; ++mt)
            #pragma unroll
            for (int nt = 0; nt < NT; ++nt)
                acc[mt][nt] = __builtin_amdgcn_mfma_f32_16x16x32_bf16(ah[mt], bl[nt], acc[mt][nt], 0, 0, 0);
    }

    // Epilogue: two phases of 32 rows.  C/D layout: col = lane&15, row = quad*4 + reg.
    constexpr int CW = NC / 8;        // cols per epilogue thread (8 threads/row)
    int er = t >> 3, q = t & 7;
    int cb = q * CW;

    #pragma unroll
    for (int p = 0; p < 2; ++p) {
        if (p) __syncthreads();       // phase-0 readers done before overwrite
        #pragma unroll
        for (int mt2 = 0; mt2 < 2; ++mt2) {
            int mt = 2 * p + mt2;
            #pragma unroll
            for (int nt = 0; nt < NT; ++nt)
                #pragma unroll
                for (int r = 0; r < 4; ++r)
                    Cb[mt2 * 16 + kg * 4 + r][w * (NC / 4) + nt * 16 + l15] = acc[mt][nt][r];
        }
        __syncthreads();

        int gr = m0 + p * 32 + er;

        if (EPI == 0) {
            if (gr < n) {
                #pragma unroll
                for (int i = 0; i < CW / 4; ++i) {
                    int c = cb + 4 * i;
                    float4 v  = *(const float4*)&Cb[er][c];
                    float4 bi = *(const float4*)&bias[c];
                    ushort4 hv = make_ushort4(f2bf(fmaxf(v.x + bi.x, 0.f)),
                                              f2bf(fmaxf(v.y + bi.y, 0.f)),
                                              f2bf(fmaxf(v.z + bi.z, 0.f)),
                                              f2bf(fmaxf(v.w + bi.w, 0.f)));
                    *(ushort4*)(Dst + (size_t)gr * DSK + c) = hv;
                }
            }
        } else if (EPI == 1) {
            float s = 0.f, ss = 0.f;
            #pragma unroll
            for (int i = 0; i < CW / 4; ++i) {
                int c = cb + 4 * i;
                float4 v  = *(const float4*)&Cb[er][c];
                float4 bi = *(const float4*)&bias[c];
                float a0 = v.x + bi.x, a1 = v.y + bi.y, a2 = v.z + bi.z, a3 = v.w + bi.w;
                s  += a0 + a1 + a2 + a3;
                ss += a0 * a0 + a1 * a1 + a2 * a2 + a3 * a3;
            }
            s  += __shfl_xor(s, 1);  s  += __shfl_xor(s, 2);  s  += __shfl_xor(s, 4);
            ss += __shfl_xor(ss, 1); ss += __shfl_xor(ss, 2); ss += __shfl_xor(ss, 4);
            float mu  = s * (1.f / NC);
            float var = ss * (1.f / NC) - mu * mu;
            float rs  = rsqrtf(var + 1e-5f);
            if (gr < n) {
                #pragma unroll
                for (int i = 0; i < CW / 4; ++i) {
                    int c = cb + 4 * i;
                    float4 v  = *(const float4*)&Cb[er][c];
                    float4 bi = *(const float4*)&bias[c];
                    float4 gg = *(const float4*)&g[c];
                    float4 bb = *(const float4*)&be[c];
                    float r0 = fmaxf((v.x + bi.x - mu) * rs * gg.x + bb.x, 0.f);
                    float r1 = fmaxf((v.y + bi.y - mu) * rs * gg.y + bb.y, 0.f);
                    float r2 = fmaxf((v.z + bi.z - mu) * rs * gg.z + bb.z, 0.f);
                    float r3 = fmaxf((v.w + bi.w - mu) * rs * gg.w + bb.w, 0.f);
                    ushort4 rh = *(const ushort4*)(Src + (size_t)gr * SSK + c);
                    ushort4 hv = make_ushort4(f2bf(bf2f(rh.x) + 0.5f * r0),
                                              f2bf(bf2f(rh.y) + 0.5f * r1),
                                              f2bf(bf2f(rh.z) + 0.5f * r2),
                                              f2bf(bf2f(rh.w) + 0.5f * r3));
                    *(ushort4*)(Dst + (size_t)gr * DSK + c) = hv;
                }
            }
        } else {
            float s = 0.f;
            #pragma unroll
            for (int i = 0; i < CW / 4; ++i) {
                int c = cb + 4 * i;
                float4 v  = *(const float4*)&Cb[er][c];
                float4 bi = *(const float4*)&bias[c];
                float4 w2 = *(const float4*)&wh2[c];
                s += fmaxf(v.x + bi.x, 0.f) * w2.x + fmaxf(v.y + bi.y, 0.f) * w2.y
                   + fmaxf(v.z + bi.z, 0.f) * w2.z + fmaxf(v.w + bi.w, 0.f) * w2.w;
            }
            s += __shfl_xor(s, 1); s += __shfl_xor(s, 2); s += __shfl_xor(s, 4);
            if (q == 0 && gr < n) outp[gr] = s + bh2[0];
        }
    }
}

// ---------------- launcher ----------------
extern "C" void kernel_launch(void* const* d_in, const int* in_sizes, int n_in,
                              void* d_out, int out_size, void* d_ws, size_t ws_size,
                              hipStream_t stream)
{
    const float* xnum = (const float*)d_in[0];
    const int*   xcat = (const int*)d_in[1];
    const int*   eidx = (const int*)d_in[2];
    const float* e0   = (const float*)d_in[3];
    const float* e1   = (const float*)d_in[4];
    const float* e2   = (const float*)d_in[5];
    const float* e3   = (const float*)d_in[6];
    const float* w_in = (const float*)d_in[7];
    const float* b_in = (const float*)d_in[8];
    const float* w1l  = (const float*)d_in[9];
    const float* b1l  = (const float*)d_in[10];
    const float* w1r  = (const float*)d_in[11];
    const float* w2l  = (const float*)d_in[12];
    const float* b2l  = (const float*)d_in[13];
    const float* w2r  = (const float*)d_in[14];
    const float* g1   = (const float*)d_in[15];
    const float* be1  = (const float*)d_in[16];
    const float* g2   = (const float*)d_in[17];
    const float* be2  = (const float*)d_in[18];
    const float* wh1  = (const float*)d_in[19];
    const float* bh1  = (const float*)d_in[20];
    const float* wh2  = (const float*)d_in[21];
    const float* bh2  = (const float*)d_in[22];

    int n = in_sizes[0] / 32;
    int ecount = in_sizes[2] / 2;
    const int* esrc = eidx;
    const int* edst = eidx + ecount;

    char* ws = (char*)d_ws;
    size_t off = 0;
    auto alloc = [&](size_t bytes) -> void* {
        void* p = ws + off;
        off += (bytes + 255) & ~(size_t)255;
        return p;
    };
    // A1: (n+1) x 256 bf16 = [mean1(128) | x0(128)]; row n = zero row for agg redirect.
    // A3 (n x 128, x2) aliases it.  A2: (n+1) x 256 = [mean2 | x1]; A0 (n x 96) aliases A2.
    unsigned short* A1 = (unsigned short*)alloc((size_t)(n + 1) * 256 * 2);
    unsigned short* A3 = A1;
    unsigned short* A2 = (unsigned short*)alloc((size_t)(n + 1) * 256 * 2);
    unsigned short* A0 = A2;
    // Weight fragment buffers (hi/lo split)
    unsigned short* w0h = (unsigned short*)alloc((size_t)96 * 128 * 2);
    unsigned short* w0l = (unsigned short*)alloc((size_t)96 * 128 * 2);
    unsigned short* w1h = (unsigned short*)alloc((size_t)256 * 128 * 2);
    unsigned short* w1lo= (unsigned short*)alloc((size_t)256 * 128 * 2);
    unsigned short* w2h = (unsigned short*)alloc((size_t)256 * 128 * 2);
    unsigned short* w2lo= (unsigned short*)alloc((size_t)256 * 128 * 2);
    unsigned short* whh = (unsigned short*)alloc((size_t)128 * 64 * 2);
    unsigned short* whl = (unsigned short*)alloc((size_t)128 * 64 * 2);
    // CSR via bucketed counting sort
    int nbuck = (n + 255) >> 8;
    int cap = ecount / nbuck + ecount / (2 * nbuck) + 256;   // mean + 50% + slack
    int* gCur    = (int*)alloc(512 * 4);
    int* bBase   = (int*)alloc(512 * 4);
    int* row_ptr = (int*)alloc((size_t)(n + 1) * 4);
    int* col     = (int*)alloc((size_t)ecount * 4);
    int2* ebuf   = (int2*)alloc((size_t)nbuck * cap * 8);
    (void)ws_size; (void)n_in; (void)out_size;

    int gemmBlocks = (n + 63) / 64;
    int aggBlocks = (n + 3) / 4;

    // merged weight prep + zero-row + gCur init (one dispatch, no memsets)
    k_prep<<<337, 256, 0, stream>>>(
        w_in, w1l, w1r, w2l, w2r, wh1,
        w0h, w0l, w1h, w1lo, w2h, w2lo, whh, whl,
        A1 + (size_t)n * 256, A2 + (size_t)n * 256, gCur);

    // input features -> A0 (bf16, 96 cols)
    k_stack0<<<((size_t)n * 6 + 255) / 256, 256, 0, stream>>>(xnum, xcat, e0, e1, e2, e3, A0, n);

    // CSR build: partition -> bucket scan -> per-bucket CSR
    int nblkP = 512;
    int chunk = (ecount + nblkP - 1) / nblkP;
    k_part<<<nblkP, 256, 0, stream>>>(esrc, edst, gCur, ebuf, ecount, chunk, cap);
    k_scanb<<<1, 512, 0, stream>>>(gCur, bBase, row_ptr, nbuck, n, ecount);
    k_bcsr<<<nbuck, 256, 0, stream>>>(ebuf, gCur, bBase, row_ptr, col, cap, n);

    // input MLP: A0[96] @ W0 -> x0 bf16 -> A1 x-slot (cols 128..255)
    k_gemm<128, 3, 0><<<gemmBlocks, 256, 0, stream>>>(
        A0, 96, w0h, w0l, b_in,
        nullptr, nullptr, nullptr, 0,
        A1 + 128, 256,
        nullptr, nullptr, nullptr, n);

    // conv1: mean of x0 -> A1 cols 0..127; GEMM A1[256] @ [w1l;w1r] -> x1 -> A2 x-slot
    k_agg<<<aggBlocks, 256, 0, stream>>>(A1 + 128, A1, 256, row_ptr, col, n, n, ecount);
    k_gemm<128, 8, 1><<<gemmBlocks, 256, 0, stream>>>(
        A1, 256, w1h, w1lo, b1l,
        g1, be1, A1 + 128, 256,
        A2 + 128, 256,
        nullptr, nullptr, nullptr, n);

    // conv2: mean of x1 -> A2 cols 0..127; GEMM A2[256] -> x2 -> A3 (128 cols/row)
    k_agg<<<aggBlocks, 256, 0, stream>>>(A2 + 128, A2, 256, row_ptr, col, n, n, ecount);
    k_gemm<128, 8, 1><<<gemmBlocks, 256, 0, stream>>>(
        A2, 256, w2h, w2lo, b2l,
        g2, be2, A2 + 128, 256,
        A3, 128,
        nullptr, nullptr, nullptr, n);

    // head: A3[128] @ wh1 -> relu -> ·wh2 + bh2 -> out
    k_gemm<64, 4, 2><<<gemmBlocks, 256, 0, stream>>>(
        A3, 128, whh, whl, bh1,
        nullptr, nullptr, nullptr, 0,
        nullptr, 0,
        wh2, bh2, (float*)d_out, n);
}

// Round 17
// 423.137 us; speedup vs baseline: 1.0724x; 1.0333x over previous
//
#include <hip/hip_runtime.h>

#define HID 128

typedef __attribute__((ext_vector_type(8))) short short8;
typedef __attribute__((ext_vector_type(4))) float f32x4;

__device__ __forceinline__ float bf2f(unsigned short u) {
    unsigned int x = ((unsigned int)u) << 16;
    return __builtin_bit_cast(float, x);
}
__device__ __forceinline__ unsigned short f2bf(float f) {
    unsigned int u = __builtin_bit_cast(unsigned int, f);
    u += 0x7fffu + ((u >> 16) & 1u);
    return (unsigned short)(u >> 16);
}

// fp32 [K,N] (optionally two stacked sources) -> fragment layout hi/lo:
// elem (k,n) at ((k/32)*N + n)*32 + k%32
__device__ __forceinline__ void prep_one(const float* __restrict__ s1, int k1,
    const float* __restrict__ s2, int N, int i,
    unsigned short* __restrict__ whi, unsigned short* __restrict__ wlo)
{
    int k = i / N, nn = i - k * N;
    float v = (k < k1) ? s1[(size_t)k * N + nn]
                       : (s2 ? s2[(size_t)(k - k1) * N + nn] : 0.f);
    unsigned short h = f2bf(v);
    unsigned short l = f2bf(v - bf2f(h));
    size_t o = ((size_t)(k >> 5) * N + nn) * 32 + (k & 31);
    whi[o] = h; wlo[o] = l;
}

// ---------------- merged prep: 4 weight preps + zero-rows + gCur + row_ptr[n] ----------------
__global__ __launch_bounds__(256) void k_prep(
    const float* __restrict__ w_in, const float* __restrict__ w1l,
    const float* __restrict__ w1r, const float* __restrict__ w2l,
    const float* __restrict__ w2r, const float* __restrict__ wh1,
    unsigned short* __restrict__ w0h, unsigned short* __restrict__ w0l,
    unsigned short* __restrict__ w1h, unsigned short* __restrict__ w1lo,
    unsigned short* __restrict__ w2h, unsigned short* __restrict__ w2lo,
    unsigned short* __restrict__ whh, unsigned short* __restrict__ whl,
    unsigned short* __restrict__ z1, unsigned short* __restrict__ z2,
    int* __restrict__ gCur, int* __restrict__ row_ptr, int n, int ecount)
{
    int b = blockIdx.x, t = threadIdx.x;
    if (b < 48) {
        prep_one(w_in, 71, nullptr, 128, b * 256 + t, w0h, w0l);
    } else if (b < 176) {
        prep_one(w1l, 128, w1r, 128, (b - 48) * 256 + t, w1h, w1lo);
    } else if (b < 304) {
        prep_one(w2l, 128, w2r, 128, (b - 176) * 256 + t, w2h, w2lo);
    } else if (b < 336) {
        prep_one(wh1, 128, nullptr, 64, (b - 304) * 256 + t, whh, whl);
    } else {
        z1[t] = 0; z2[t] = 0;
        gCur[t] = 0; gCur[t + 256] = 0;
        if (t == 0) row_ptr[n] = ecount;
    }
}

// ---------------- M1: edge partition (blocks [0,512)) ‖ feature prestack (rest) ----------------
// Independent chains overlapped in one dispatch: latency-bound scatter + copy co-schedule.
__global__ __launch_bounds__(256) void k_m1(
    const int* __restrict__ esrc, const int* __restrict__ edst,
    int* __restrict__ gCur, int2* __restrict__ ebuf, int ecount, int chunk, int cap,
    const float* __restrict__ xnum, const int* __restrict__ xcat,
    const float* __restrict__ e0, const float* __restrict__ e1,
    const float* __restrict__ e2, const float* __restrict__ e3,
    unsigned short* __restrict__ A0, int n)
{
    __shared__ int hist[512];
    __shared__ int base[512];
    int t = threadIdx.x;
    if (blockIdx.x < 512) {
        // ---- k_part body: bucket = dst>>8, scatter to per-bucket regions ----
        hist[t] = 0; hist[t + 256] = 0;
        __syncthreads();
        int start = blockIdx.x * chunk;
        int end = start + chunk < ecount ? start + chunk : ecount;
        for (int i = start + t; i < end; i += 256)
            atomicAdd(&hist[edst[i] >> 8], 1);          // LDS
        __syncthreads();
        for (int bk = t; bk < 512; bk += 256) {
            int h = hist[bk];
            base[bk] = h ? atomicAdd(&gCur[bk], h) : 0; // global, 1 per (block,bucket)
            hist[bk] = 0;
        }
        __syncthreads();
        for (int i = start + t; i < end; i += 256) {
            int d = edst[i];
            int b = d >> 8;
            int slot = atomicAdd(&hist[b], 1);          // LDS
            int pos = base[b] + slot;
            if (pos < cap)
                ebuf[(size_t)b * cap + pos] = make_int2(esrc[i], d);
        }
    } else {
        // ---- k_stack0 body: [xnum | emb0..3 | pad] -> bf16 A0[n][96] ----
        int g = (blockIdx.x - 512) * 256 + t;
        int r = g / 6, c = g - r * 6;
        if (r >= n) return;
        int4 cc = ((const int4*)xcat)[r];
        float v[16];
        int cbase = c * 16;
        #pragma unroll
        for (int j = 0; j < 16; ++j) {
            int col = cbase + j;
            float val;
            if      (col < 32) val = xnum[(size_t)r * 32 + col];
            else if (col < 42) val = e0[(size_t)cc.x * 10 + (col - 32)];
            else if (col < 48) val = e1[(size_t)cc.y * 6  + (col - 42)];
            else if (col < 53) val = e2[(size_t)cc.z * 5  + (col - 48)];
            else if (col < 71) val = e3[(size_t)cc.w * 18 + (col - 53)];
            else               val = 0.f;
            v[j] = val;
        }
        unsigned int ph[8];
        #pragma unroll
        for (int j = 0; j < 8; ++j)
            ph[j] = (unsigned int)f2bf(v[2*j]) | ((unsigned int)f2bf(v[2*j+1]) << 16);
        unsigned int* dh = (unsigned int*)(A0 + (size_t)r * 96 + cbase);
        uint4 a; a.x = ph[0]; a.y = ph[1]; a.z = ph[2]; a.w = ph[3];
        uint4 bb; bb.x = ph[4]; bb.y = ph[5]; bb.z = ph[6]; bb.w = ph[7];
        ((uint4*)dh)[0] = a; ((uint4*)dh)[1] = bb;
    }
}

// ---------------- M2: input GEMM (blocks [0,gemmBlocks)) ‖ per-bucket CSR (rest) ----------------
// Both depend only on M1.  bcsr blocks self-compute their bucket base from gCur
// (512 L2-hot loads + LDS reduce) — k_scanb dispatch eliminated.
__global__ __launch_bounds__(256) void k_m2(
    const unsigned short* __restrict__ A,            // A0, SK=96
    const unsigned short* __restrict__ Whi, const unsigned short* __restrict__ Wlo,
    const float* __restrict__ bias,
    unsigned short* __restrict__ Dst,                // x0, DSK=256
    int n, int gemmBlocks,
    const int2* __restrict__ ebuf, const int* __restrict__ gCur,
    int* __restrict__ row_ptr, int* __restrict__ col, int cap)
{
    __shared__ float Cb[32][132];
    __shared__ int h2[256];
    __shared__ int sm2[256];
    int t = threadIdx.x;

    if ((int)blockIdx.x < gemmBlocks) {
        // ---- input GEMM body: NC=128, KT8=3, EPI=0, SK=96, DSK=256 ----
        int lane = t & 63, w = t >> 6;
        int l15 = lane & 15, kg = lane >> 4;
        int m0 = blockIdx.x * 64;

        size_t aoff[4];
        #pragma unroll
        for (int mt = 0; mt < 4; ++mt) {
            int r = m0 + mt * 16 + l15;
            r = r < n ? r : n - 1;
            aoff[mt] = (size_t)r * 96 + kg * 8;
        }
        size_t nb[2];
        #pragma unroll
        for (int nt = 0; nt < 2; ++nt)
            nb[nt] = (size_t)(w * 32 + nt * 16 + l15) * 32 + kg * 8;

        f32x4 acc[4][2];
        #pragma unroll
        for (int mt = 0; mt < 4; ++mt)
            #pragma unroll
            for (int nt = 0; nt < 2; ++nt)
                acc[mt][nt] = (f32x4)(0.f);

        #pragma unroll 1
        for (int s = 0; s < 3; ++s) {
            int koff = s * 32;
            short8 ah[4];
            #pragma unroll
            for (int mt = 0; mt < 4; ++mt)
                ah[mt] = *(const short8*)(A + aoff[mt] + koff);
            short8 bh[2], bl[2];
            #pragma unroll
            for (int nt = 0; nt < 2; ++nt) {
                bh[nt] = *(const short8*)(Whi + (size_t)s * 128 * 32 + nb[nt]);
                bl[nt] = *(const short8*)(Wlo + (size_t)s * 128 * 32 + nb[nt]);
            }
            #pragma unroll
            for (int mt = 0; mt < 4; ++mt)
                #pragma unroll
                for (int nt = 0; nt < 2; ++nt)
                    acc[mt][nt] = __builtin_amdgcn_mfma_f32_16x16x32_bf16(ah[mt], bh[nt], acc[mt][nt], 0, 0, 0);
            #pragma unroll
            for (int mt = 0; mt < 4; ++mt)
                #pragma unroll
                for (int nt = 0; nt < 2; ++nt)
                    acc[mt][nt] = __builtin_amdgcn_mfma_f32_16x16x32_bf16(ah[mt], bl[nt], acc[mt][nt], 0, 0, 0);
        }

        int er = t >> 3, q = t & 7;
        int cb = q * 16;
        #pragma unroll
        for (int p = 0; p < 2; ++p) {
            if (p) __syncthreads();
            #pragma unroll
            for (int mt2 = 0; mt2 < 2; ++mt2) {
                int mt = 2 * p + mt2;
                #pragma unroll
                for (int nt = 0; nt < 2; ++nt)
                    #pragma unroll
                    for (int r = 0; r < 4; ++r)
                        Cb[mt2 * 16 + kg * 4 + r][w * 32 + nt * 16 + l15] = acc[mt][nt][r];
            }
            __syncthreads();
            int gr = m0 + p * 32 + er;
            if (gr < n) {
                #pragma unroll
                for (int i = 0; i < 4; ++i) {
                    int c = cb + 4 * i;
                    float4 v  = *(const float4*)&Cb[er][c];
                    float4 bi = *(const float4*)&bias[c];
                    ushort4 hv = make_ushort4(f2bf(fmaxf(v.x + bi.x, 0.f)),
                                              f2bf(fmaxf(v.y + bi.y, 0.f)),
                                              f2bf(fmaxf(v.z + bi.z, 0.f)),
                                              f2bf(fmaxf(v.w + bi.w, 0.f)));
                    *(ushort4*)(Dst + (size_t)gr * 256 + c) = hv;
                }
            }
        }
    } else {
        // ---- bcsr body with self-computed bucket base ----
        int b = blockIdx.x - gemmBlocks;
        // bucket base = sum gCur[j] for j < b
        int partial = 0;
        if (t < b) partial += gCur[t];
        if (t + 256 < b) partial += gCur[t + 256];
        sm2[t] = partial;
        __syncthreads();
        for (int d = 128; d > 0; d >>= 1) {
            if (t < d) sm2[t] += sm2[t + d];
            __syncthreads();
        }
        int gb = sm2[0];
        __syncthreads();

        int cnt = gCur[b];
        int nb0 = b << 8;
        const int2* eb = ebuf + (size_t)b * cap;
        h2[t] = 0;
        __syncthreads();
        for (int i = t; i < cnt; i += 256)
            atomicAdd(&h2[eb[i].y & 255], 1);           // LDS histogram
        __syncthreads();
        int hv = h2[t];
        sm2[t] = hv;
        __syncthreads();
        for (int d = 1; d < 256; d <<= 1) {
            int v = (t >= d) ? sm2[t - d] : 0;
            __syncthreads();
            sm2[t] += v;
            __syncthreads();
        }
        int excl = sm2[t] - hv;
        int g = nb0 + t;
        if (g < n) row_ptr[g] = gb + excl;
        __syncthreads();
        h2[t] = excl;                                   // reuse as cursor
        __syncthreads();
        for (int i = t; i < cnt; i += 256) {
            int2 e = eb[i];
            int slot = atomicAdd(&h2[e.y & 255], 1);    // LDS
            col[gb + slot] = e.x;
        }
    }
}

// ---------------- mean aggregation (bf16): quarter-wave per edge ----------------
// 16 lanes x uint4 cover a 256 B row; ALWAYS 4 gathers in flight — out-of-range
// edges redirect to zero row `zr` (branchless, address-clamped col loads).
__global__ __launch_bounds__(256) void k_agg(
    const unsigned short* __restrict__ xh, unsigned short* __restrict__ mh, int SK,
    const int* __restrict__ row_ptr, const int* __restrict__ col, int n,
    int zr, int emax)
{
    int lane = threadIdx.x & 63;
    int qw  = lane >> 4;
    int l16 = lane & 15;
    int node = blockIdx.x * 4 + (threadIdx.x >> 6);
    if (node >= n) return;
    node = __builtin_amdgcn_readfirstlane(node);
    int s = row_ptr[node], e = row_ptr[node + 1];
    int deg = e - s;
    float a0 = 0.f, a1 = 0.f, a2 = 0.f, a3 = 0.f;
    float a4 = 0.f, a5 = 0.f, a6 = 0.f, a7 = 0.f;
    size_t cOff = (size_t)l16 * 8;        // 8 bf16 cols per lane

    auto accum = [&](uint4 r) {
        a0 += __builtin_bit_cast(float, r.x << 16);
        a1 += __builtin_bit_cast(float, r.x & 0xffff0000u);
        a2 += __builtin_bit_cast(float, r.y << 16);
        a3 += __builtin_bit_cast(float, r.y & 0xffff0000u);
        a4 += __builtin_bit_cast(float, r.z << 16);
        a5 += __builtin_bit_cast(float, r.z & 0xffff0000u);
        a6 += __builtin_bit_cast(float, r.w << 16);
        a7 += __builtin_bit_cast(float, r.w & 0xffff0000u);
    };

    int em1 = emax - 1;
    for (int p = s + qw; p < e; p += 16) {
        int p1 = p + 4, p2 = p + 8, p3 = p + 12;
        int q1 = p1 < em1 ? p1 : em1;
        int q2 = p2 < em1 ? p2 : em1;
        int q3 = p3 < em1 ? p3 : em1;
        int t0 = col[p];
        int t1 = col[q1];
        int t2 = col[q2];
        int t3 = col[q3];
        int c0 = t0;
        int c1 = (p1 < e) ? t1 : zr;
        int c2 = (p2 < e) ? t2 : zr;
        int c3 = (p3 < e) ? t3 : zr;
        uint4 r0 = *(const uint4*)(xh + (size_t)c0 * SK + cOff);
        uint4 r1 = *(const uint4*)(xh + (size_t)c1 * SK + cOff);
        uint4 r2 = *(const uint4*)(xh + (size_t)c2 * SK + cOff);
        uint4 r3 = *(const uint4*)(xh + (size_t)c3 * SK + cOff);
        accum(r0); accum(r1); accum(r2); accum(r3);
    }

    a0 += __shfl_xor(a0, 16); a0 += __shfl_xor(a0, 32);
    a1 += __shfl_xor(a1, 16); a1 += __shfl_xor(a1, 32);
    a2 += __shfl_xor(a2, 16); a2 += __shfl_xor(a2, 32);
    a3 += __shfl_xor(a3, 16); a3 += __shfl_xor(a3, 32);
    a4 += __shfl_xor(a4, 16); a4 += __shfl_xor(a4, 32);
    a5 += __shfl_xor(a5, 16); a5 += __shfl_xor(a5, 32);
    a6 += __shfl_xor(a6, 16); a6 += __shfl_xor(a6, 32);
    a7 += __shfl_xor(a7, 16); a7 += __shfl_xor(a7, 32);

    if (qw == 0) {
        float inv = 1.f / (float)(deg > 1 ? deg : 1);
        uint4 o;
        o.x = (unsigned int)f2bf(a0 * inv) | ((unsigned int)f2bf(a1 * inv) << 16);
        o.y = (unsigned int)f2bf(a2 * inv) | ((unsigned int)f2bf(a3 * inv) << 16);
        o.z = (unsigned int)f2bf(a4 * inv) | ((unsigned int)f2bf(a5 * inv) << 16);
        o.w = (unsigned int)f2bf(a6 * inv) | ((unsigned int)f2bf(a7 * inv) << 16);
        *(uint4*)(mh + (size_t)node * SK + cOff) = o;
    }
}

// ---------------- split-weight bf16-activation MFMA GEMM, M-tile=64, block=256 ----------------
// Best-known config (r13): r12 prefetch, r14 M=32, r15 LDS head-fusion all regressed.
// A row-major bf16 [m][SK], SK = KT8*32.  Weights split hi/lo.
// K-loop (#pragma unroll 1): per k-tile load ah,bh,bl once; groups Ah·Wh, Ah·Wl.
// Epilogue in 2 phases of 32 rows (LDS 16.9 KB), 8 threads/row.
// EPI 1: LN+relu, out = res + 0.5*r -> bf16 store.  EPI 2: head -> outp fp32.
template<int NC, int KT8, int EPI>
__global__ __launch_bounds__(256) void k_gemm(
    const unsigned short* __restrict__ A, int SK,
    const unsigned short* __restrict__ Whi, const unsigned short* __restrict__ Wlo,
    const float* __restrict__ bias,
    const float* __restrict__ g, const float* __restrict__ be,
    const unsigned short* __restrict__ Src, int SSK,
    unsigned short* __restrict__ Dst, int DSK,
    const float* __restrict__ wh2, const float* __restrict__ bh2, float* __restrict__ outp,
    int n)
{
    constexpr int NT = NC / 64;       // n-16-tiles per wave
    __shared__ float Cb[32][NC + 4];
    int t = threadIdx.x;
    int lane = t & 63, w = t >> 6;
    int l15 = lane & 15, kg = lane >> 4;
    int m0 = blockIdx.x * 64;

    size_t aoff[4];
    #pragma unroll
    for (int mt = 0; mt < 4; ++mt) {
        int r = m0 + mt * 16 + l15;
        r = r < n ? r : n - 1;
        aoff[mt] = (size_t)r * SK + kg * 8;
    }
    size_t nb[NT];
    #pragma unroll
    for (int nt = 0; nt < NT; ++nt)
        nb[nt] = (size_t)(w * (NC / 4) + nt * 16 + l15) * 32 + kg * 8;

    f32x4 acc[4][NT];
    #pragma unroll
    for (int mt = 0; mt < 4; ++mt)
        #pragma unroll
        for (int nt = 0; nt < NT; ++nt)
            acc[mt][nt] = (f32x4)(0.f);

    #pragma unroll 1
    for (int s = 0; s < KT8; ++s) {
        int koff = s * 32;
        short8 ah[4];
        #pragma unroll
        for (int mt = 0; mt < 4; ++mt)
            ah[mt] = *(const short8*)(A + aoff[mt] + koff);
        short8 bh[NT], bl[NT];
        #pragma unroll
        for (int nt = 0; nt < NT; ++nt) {
            bh[nt] = *(const short8*)(Whi + (size_t)s * NC * 32 + nb[nt]);
            bl[nt] = *(const short8*)(Wlo + (size_t)s * NC * 32 + nb[nt]);
        }
        #pragma unroll
        for (int mt = 0; mt < 4; ++mt)
            #pragma unroll
            for (int nt = 0; nt < NT; ++nt)
                acc[mt][nt] = __builtin_amdgcn_mfma_f32_16x16x32_bf16(ah[mt], bh[nt], acc[mt][nt], 0, 0, 0);
        #pragma unroll
        for (int mt = 0; mt < 4; ++mt)
            #pragma unroll
            for (int nt = 0; nt < NT; ++nt)
                acc[mt][nt] = __builtin_amdgcn_mfma_f32_16x16x32_bf16(ah[mt], bl[nt], acc[mt][nt], 0, 0, 0);
    }

    // Epilogue: two phases of 32 rows.  C/D layout: col = lane&15, row = quad*4 + reg.
    constexpr int CW = NC / 8;        // cols per epilogue thread (8 threads/row)
    int er = t >> 3, q = t & 7;
    int cb = q * CW;

    #pragma unroll
    for (int p = 0; p < 2; ++p) {
        if (p) __syncthreads();       // phase-0 readers done before overwrite
        #pragma unroll
        for (int mt2 = 0; mt2 < 2; ++mt2) {
            int mt = 2 * p + mt2;
            #pragma unroll
            for (int nt = 0; nt < NT; ++nt)
                #pragma unroll
                for (int r = 0; r < 4; ++r)
                    Cb[mt2 * 16 + kg * 4 + r][w * (NC / 4) + nt * 16 + l15] = acc[mt][nt][r];
        }
        __syncthreads();

        int gr = m0 + p * 32 + er;

        if (EPI == 1) {
            float s = 0.f, ss = 0.f;
            #pragma unroll
            for (int i = 0; i < CW / 4; ++i) {
                int c = cb + 4 * i;
                float4 v  = *(const float4*)&Cb[er][c];
                float4 bi = *(const float4*)&bias[c];
                float a0 = v.x + bi.x, a1 = v.y + bi.y, a2 = v.z + bi.z, a3 = v.w + bi.w;
                s  += a0 + a1 + a2 + a3;
                ss += a0 * a0 + a1 * a1 + a2 * a2 + a3 * a3;
            }
            s  += __shfl_xor(s, 1);  s  += __shfl_xor(s, 2);  s  += __shfl_xor(s, 4);
            ss += __shfl_xor(ss, 1); ss += __shfl_xor(ss, 2); ss += __shfl_xor(ss, 4);
            float mu  = s * (1.f / NC);
            float var = ss * (1.f / NC) - mu * mu;
            float rs  = rsqrtf(var + 1e-5f);
            if (gr < n) {
                #pragma unroll
                for (int i = 0; i < CW / 4; ++i) {
                    int c = cb + 4 * i;
                    float4 v  = *(const float4*)&Cb[er][c];
                    float4 bi = *(const float4*)&bias[c];
                    float4 gg = *(const float4*)&g[c];
                    float4 bb = *(const float4*)&be[c];
                    float r0 = fmaxf((v.x + bi.x - mu) * rs * gg.x + bb.x, 0.f);
                    float r1 = fmaxf((v.y + bi.y - mu) * rs * gg.y + bb.y, 0.f);
                    float r2 = fmaxf((v.z + bi.z - mu) * rs * gg.z + bb.z, 0.f);
                    float r3 = fmaxf((v.w + bi.w - mu) * rs * gg.w + bb.w, 0.f);
                    ushort4 rh = *(const ushort4*)(Src + (size_t)gr * SSK + c);
                    ushort4 hv = make_ushort4(f2bf(bf2f(rh.x) + 0.5f * r0),
                                              f2bf(bf2f(rh.y) + 0.5f * r1),
                                              f2bf(bf2f(rh.z) + 0.5f * r2),
                                              f2bf(bf2f(rh.w) + 0.5f * r3));
                    *(ushort4*)(Dst + (size_t)gr * DSK + c) = hv;
                }
            }
        } else {
            float s = 0.f;
            #pragma unroll
            for (int i = 0; i < CW / 4; ++i) {
                int c = cb + 4 * i;
                float4 v  = *(const float4*)&Cb[er][c];
                float4 bi = *(const float4*)&bias[c];
                float4 w2 = *(const float4*)&wh2[c];
                s += fmaxf(v.x + bi.x, 0.f) * w2.x + fmaxf(v.y + bi.y, 0.f) * w2.y
                   + fmaxf(v.z + bi.z, 0.f) * w2.z + fmaxf(v.w + bi.w, 0.f) * w2.w;
            }
            s += __shfl_xor(s, 1); s += __shfl_xor(s, 2); s += __shfl_xor(s, 4);
            if (q == 0 && gr < n) outp[gr] = s + bh2[0];
        }
    }
}

// ---------------- launcher ----------------
extern "C" void kernel_launch(void* const* d_in, const int* in_sizes, int n_in,
                              void* d_out, int out_size, void* d_ws, size_t ws_size,
                              hipStream_t stream)
{
    const float* xnum = (const float*)d_in[0];
    const int*   xcat = (const int*)d_in[1];
    const int*   eidx = (const int*)d_in[2];
    const float* e0   = (const float*)d_in[3];
    const float* e1   = (const float*)d_in[4];
    const float* e2   = (const float*)d_in[5];
    const float* e3   = (const float*)d_in[6];
    const float* w_in = (const float*)d_in[7];
    const float* b_in = (const float*)d_in[8];
    const float* w1l  = (const float*)d_in[9];
    const float* b1l  = (const float*)d_in[10];
    const float* w1r  = (const float*)d_in[11];
    const float* w2l  = (const float*)d_in[12];
    const float* b2l  = (const float*)d_in[13];
    const float* w2r  = (const float*)d_in[14];
    const float* g1   = (const float*)d_in[15];
    const float* be1  = (const float*)d_in[16];
    const float* g2   = (const float*)d_in[17];
    const float* be2  = (const float*)d_in[18];
    const float* wh1  = (const float*)d_in[19];
    const float* bh1  = (const float*)d_in[20];
    const float* wh2  = (const float*)d_in[21];
    const float* bh2  = (const float*)d_in[22];

    int n = in_sizes[0] / 32;
    int ecount = in_sizes[2] / 2;
    const int* esrc = eidx;
    const int* edst = eidx + ecount;

    char* ws = (char*)d_ws;
    size_t off = 0;
    auto alloc = [&](size_t bytes) -> void* {
        void* p = ws + off;
        off += (bytes + 255) & ~(size_t)255;
        return p;
    };
    // A1: (n+1) x 256 bf16 = [mean1(128) | x0(128)]; row n = zero row for agg redirect.
    // A3 (n x 128, x2) aliases it.  A2: (n+1) x 256 = [mean2 | x1]; A0 (n x 96) aliases A2.
    unsigned short* A1 = (unsigned short*)alloc((size_t)(n + 1) * 256 * 2);
    unsigned short* A3 = A1;
    unsigned short* A2 = (unsigned short*)alloc((size_t)(n + 1) * 256 * 2);
    unsigned short* A0 = A2;
    // Weight fragment buffers (hi/lo split)
    unsigned short* w0h = (unsigned short*)alloc((size_t)96 * 128 * 2);
    unsigned short* w0l = (unsigned short*)alloc((size_t)96 * 128 * 2);
    unsigned short* w1h = (unsigned short*)alloc((size_t)256 * 128 * 2);
    unsigned short* w1lo= (unsigned short*)alloc((size_t)256 * 128 * 2);
    unsigned short* w2h = (unsigned short*)alloc((size_t)256 * 128 * 2);
    unsigned short* w2lo= (unsigned short*)alloc((size_t)256 * 128 * 2);
    unsigned short* whh = (unsigned short*)alloc((size_t)128 * 64 * 2);
    unsigned short* whl = (unsigned short*)alloc((size_t)128 * 64 * 2);
    // CSR via bucketed counting sort
    int nbuck = (n + 255) >> 8;
    int cap = ecount / nbuck + ecount / (2 * nbuck) + 256;   // mean + 50% + slack
    int* gCur    = (int*)alloc(512 * 4);
    int* row_ptr = (int*)alloc((size_t)(n + 1) * 4);
    int* col     = (int*)alloc((size_t)ecount * 4);
    int2* ebuf   = (int2*)alloc((size_t)nbuck * cap * 8);
    (void)ws_size; (void)n_in; (void)out_size;

    int gemmBlocks = (n + 63) / 64;
    int aggBlocks = (n + 3) / 4;
    int stackBlocks = ((size_t)n * 6 + 255) / 256;
    int nblkP = 512;
    int chunk = (ecount + nblkP - 1) / nblkP;

    // prep: weights + zero rows + gCur + row_ptr[n]
    k_prep<<<337, 256, 0, stream>>>(
        w_in, w1l, w1r, w2l, w2r, wh1,
        w0h, w0l, w1h, w1lo, w2h, w2lo, whh, whl,
        A1 + (size_t)n * 256, A2 + (size_t)n * 256, gCur, row_ptr, n, ecount);

    // M1: edge partition ‖ feature prestack
    k_m1<<<512 + stackBlocks, 256, 0, stream>>>(
        esrc, edst, gCur, ebuf, ecount, chunk, cap,
        xnum, xcat, e0, e1, e2, e3, A0, n);

    // M2: input GEMM (A0 @ W0 -> x0 in A1 cols 128..255) ‖ per-bucket CSR build
    k_m2<<<gemmBlocks + nbuck, 256, 0, stream>>>(
        A0, w0h, w0l, b_in, A1 + 128, n, gemmBlocks,
        ebuf, gCur, row_ptr, col, cap);

    // conv1: mean of x0 -> A1 cols 0..127; GEMM A1[256] @ [w1l;w1r] -> x1 -> A2 x-slot
    k_agg<<<aggBlocks, 256, 0, stream>>>(A1 + 128, A1, 256, row_ptr, col, n, n, ecount);
    k_gemm<128, 8, 1><<<gemmBlocks, 256, 0, stream>>>(
        A1, 256, w1h, w1lo, b1l,
        g1, be1, A1 + 128, 256,
        A2 + 128, 256,
        nullptr, nullptr, nullptr, n);

    // conv2: mean of x1 -> A2 cols 0..127; GEMM A2[256] -> x2 -> A3 (128 cols/row)
    k_agg<<<aggBlocks, 256, 0, stream>>>(A2 + 128, A2, 256, row_ptr, col, n, n, ecount);
    k_gemm<128, 8, 1><<<gemmBlocks, 256, 0, stream>>>(
        A2, 256, w2h, w2lo, b2l,
        g2, be2, A2 + 128, 256,
        A3, 128,
        nullptr, nullptr, nullptr, n);

    // head: A3[128] @ wh1 -> relu -> ·wh2 + bh2 -> out
    k_gemm<64, 4, 2><<<gemmBlocks, 256, 0, stream>>>(
        A3, 128, whh, whl, bh1,
        nullptr, nullptr, nullptr, 0,
        nullptr, 0,
        wh2, bh2, (float*)d_out, n);
}